// Round 4
// baseline (367.130 us; speedup 1.0000x reference)
//
#include <hip/hip_runtime.h>
#include <cmath>

typedef __attribute__((ext_vector_type(8))) short  short8;
typedef __attribute__((ext_vector_type(4))) float  floatx4;
typedef __attribute__((ext_vector_type(8))) unsigned short ushort8;
typedef __attribute__((ext_vector_type(8))) unsigned char uchar8v;

// Accumulator slots spread 64B apart to avoid same-cacheline atomic serialization.
#define SLOT(i) ((i) * 16)
#define ACC_L1   0
#define ACC_MSE  1
#define ACC_ST0  2
#define ACC_ST1  3
#define ACC_SP0  4
#define ACC_SP1  5
#define ACC_HV   6
#define ACC_WV   7
#define ACC_EXP  8
#define ACC_SPAT 9
#define ACC_PERC 10
#define SSIM_SLOT(scale, cs, img) (256 + ((scale) * 12 + (cs) * 6 + (img)) * 16)

struct GW { float g[11]; };

__device__ __forceinline__ float waveSum(float v) {
#pragma unroll
  for (int o = 32; o > 0; o >>= 1) v += __shfl_down(v, o, 64);
  return v;
}

__device__ __forceinline__ float blockSum256(float v) {
  __shared__ float red[4];
  const int tid = threadIdx.x;
  v = waveSum(v);
  __syncthreads();
  if ((tid & 63) == 0) red[tid >> 6] = v;
  __syncthreads();
  return red[0] + red[1] + red[2] + red[3];
}

// pack 4 floats -> 4 OCP e4m3 bytes (HW cvt, RNE)
__device__ __forceinline__ unsigned int pk_fp8x4(float v0, float v1, float v2, float v3) {
  int p = __builtin_amdgcn_cvt_pk_fp8_f32(v0, v1, 0, false);
  p = __builtin_amdgcn_cvt_pk_fp8_f32(v2, v3, p, true);
  return (unsigned int)p;
}

// ---------------- small loss terms ----------------

// one float4 per thread; grid 294 blocks x 256 = 75264 float4 = full tensor.
__global__ __launch_bounds__(256) void basic_stats(const float* __restrict__ yt,
                                                   const float* __restrict__ yp,
                                                   float* __restrict__ acc) {
  const int i4 = blockIdx.x * 256 + threadIdx.x;  // 0..75263
  const int idx = i4 * 4;
  const float4 t4 = *(const float4*)(yt + idx);
  const float4 p4 = *(const float4*)(yp + idx);
  float l1 = 0.f, mse = 0.f, st0 = 0.f, st1 = 0.f, sp0 = 0.f, sp1 = 0.f, hv = 0.f, wv = 0.f;
#define BTERM(tt, pp) { const float d = (pp) - (tt); const float ad = fabsf(d); \
                        l1 += (ad < 1.f) ? 0.5f * d * d : ad - 0.5f; mse += d * d; }
  BTERM(t4.x, p4.x) BTERM(t4.y, p4.y) BTERM(t4.z, p4.z) BTERM(t4.w, p4.w)
#undef BTERM
  const float ts = t4.x + t4.y + t4.z + t4.w;
  const float ps = p4.x + p4.y + p4.z + p4.w;
  if (i4 < 37632) { st0 = ts; sp0 = ps; } else { st1 = ts; sp1 = ps; }
  const int h = (idx / 224) % 224;
  if (h < 223) {
    const float4 pn = *(const float4*)(yp + idx + 224);
    float d;
    d = pn.x - p4.x; hv += d * d;
    d = pn.y - p4.y; hv += d * d;
    d = pn.z - p4.z; hv += d * d;
    d = pn.w - p4.w; hv += d * d;
  }
  {
    const int w = idx % 224;  // 0,4,...,220
    float d;
    d = p4.y - p4.x; wv += d * d;
    d = p4.z - p4.y; wv += d * d;
    d = p4.w - p4.z; wv += d * d;
    if (w < 220) { d = yp[idx + 4] - p4.w; wv += d * d; }
  }
  float s;
  s = blockSum256(l1);  if (threadIdx.x == 0) atomicAdd(acc + SLOT(ACC_L1), s);
  s = blockSum256(mse); if (threadIdx.x == 0) atomicAdd(acc + SLOT(ACC_MSE), s);
  s = blockSum256(st0); if (threadIdx.x == 0) atomicAdd(acc + SLOT(ACC_ST0), s);
  s = blockSum256(st1); if (threadIdx.x == 0) atomicAdd(acc + SLOT(ACC_ST1), s);
  s = blockSum256(sp0); if (threadIdx.x == 0) atomicAdd(acc + SLOT(ACC_SP0), s);
  s = blockSum256(sp1); if (threadIdx.x == 0) atomicAdd(acc + SLOT(ACC_SP1), s);
  s = blockSum256(hv);  if (threadIdx.x == 0) atomicAdd(acc + SLOT(ACC_HV), s);
  s = blockSum256(wv);  if (threadIdx.x == 0) atomicAdd(acc + SLOT(ACC_WV), s);
}

__global__ __launch_bounds__(256) void pool4_lum_k(const float* __restrict__ yt,
                                                   const float* __restrict__ yp,
                                                   float* __restrict__ op,
                                                   float* __restrict__ ep) {
  const int idx = blockIdx.x * 256 + threadIdx.x;
  if (idx >= 2 * 56 * 56) return;
  const int b = idx / 3136;
  const int rem = idx - b * 3136;
  const int r = rem / 56, cl = rem - r * 56;
  float so = 0.f, se = 0.f;
  for (int c = 0; c < 3; ++c)
#pragma unroll
    for (int dy = 0; dy < 4; ++dy) {
      const size_t off = (((size_t)b * 3 + c) * 224 + (r * 4 + dy)) * 224 + cl * 4;
      const float4 a = *(const float4*)(yt + off);
      const float4 e = *(const float4*)(yp + off);
      so += a.x + a.y + a.z + a.w;
      se += e.x + e.y + e.z + e.w;
    }
  op[idx] = so * (1.f / 48.f);
  ep[idx] = se * (1.f / 48.f);
}

// spat + exposure fused (exposure tile = 4x4 mean of ep; algebraically = 16x16/768 mean)
__global__ __launch_bounds__(256) void spat_k(const float* __restrict__ op,
                                              const float* __restrict__ ep,
                                              float* __restrict__ acc) {
  const int idx = blockIdx.x * 256 + threadIdx.x;
  float v = 0.f;
  if (idx < 6272) {
    const int rem = idx % 3136;
    const int r = rem / 56, cl = rem - r * 56;
    const float oc = op[idx], ec = ep[idx];
    const float ol = (cl > 0)  ? op[idx - 1]  : 0.f;
    const float el = (cl > 0)  ? ep[idx - 1]  : 0.f;
    const float orr = (cl < 55) ? op[idx + 1]  : 0.f;
    const float er  = (cl < 55) ? ep[idx + 1]  : 0.f;
    const float ou = (r > 0)   ? op[idx - 56] : 0.f;
    const float eu = (r > 0)   ? ep[idx - 56] : 0.f;
    const float od = (r < 55)  ? op[idx + 56] : 0.f;
    const float ed = (r < 55)  ? ep[idx + 56] : 0.f;
    float d;
    d = (oc - ol) - (ec - el);   v += d * d;
    d = (oc - orr) - (ec - er);  v += d * d;
    d = (oc - ou) - (ec - eu);   v += d * d;
    d = (oc - od) - (ec - ed);   v += d * d;
  }
  const float t = blockSum256(v);
  if (threadIdx.x == 0) atomicAdd(acc + SLOT(ACC_SPAT), t);
  if (idx < 392) {
    const int b = idx / 196;
    const int rem = idx - b * 196;
    const int py = rem / 14, px = rem - py * 14;
    float ssum = 0.f;
#pragma unroll
    for (int dy = 0; dy < 4; ++dy)
#pragma unroll
      for (int dx = 0; dx < 4; ++dx)
        ssum += ep[b * 3136 + (py * 4 + dy) * 56 + px * 4 + dx];
    const float m = ssum * (1.f / 16.f) - 0.6f;
    atomicAdd(acc + SLOT(ACC_EXP), m * m);
  }
}

// ---------------- MS-SSIM: fused pyramid + single all-scale launch ----------------

// one block = one 16x16 source tile of one (tensor, img); produces all 4 levels
// hierarchically (same 0.25*(a+b+c+d) order as cascaded down2).
__global__ __launch_bounds__(256) void pyramid_k(const float* __restrict__ yt,
                                                 const float* __restrict__ yp,
                                                 float* __restrict__ pyrX,
                                                 float* __restrict__ pyrY) {
  __shared__ float sA[16][17];
  __shared__ float s1[8][9];
  __shared__ float s2[4][5];
  __shared__ float s3[2][3];
  const int tid = threadIdx.x;
  const int img = blockIdx.y;
  const int ty = blockIdx.x / 14, tx = blockIdx.x - ty * 14;
  const float* src = (blockIdx.z ? yp : yt) + (size_t)img * 224 * 224;
  float* dst = blockIdx.z ? pyrY : pyrX;
  const int r = tid >> 4, c = tid & 15;
  sA[r][c] = src[(size_t)(ty * 16 + r) * 224 + tx * 16 + c];
  __syncthreads();
  if (tid < 64) {
    const int r1 = tid >> 3, c1 = tid & 7;
    const float m = 0.25f * (sA[2 * r1][2 * c1] + sA[2 * r1][2 * c1 + 1] +
                             sA[2 * r1 + 1][2 * c1] + sA[2 * r1 + 1][2 * c1 + 1]);
    dst[(size_t)img * 12544 + (ty * 8 + r1) * 112 + tx * 8 + c1] = m;
    s1[r1][c1] = m;
  }
  __syncthreads();
  if (tid < 16) {
    const int r2 = tid >> 2, c2 = tid & 3;
    const float m = 0.25f * (s1[2 * r2][2 * c2] + s1[2 * r2][2 * c2 + 1] +
                             s1[2 * r2 + 1][2 * c2] + s1[2 * r2 + 1][2 * c2 + 1]);
    dst[75264 + (size_t)img * 3136 + (ty * 4 + r2) * 56 + tx * 4 + c2] = m;
    s2[r2][c2] = m;
  }
  __syncthreads();
  if (tid < 4) {
    const int r3 = tid >> 1, c3 = tid & 1;
    const float m = 0.25f * (s2[2 * r3][2 * c3] + s2[2 * r3][2 * c3 + 1] +
                             s2[2 * r3 + 1][2 * c3] + s2[2 * r3 + 1][2 * c3 + 1]);
    dst[94080 + (size_t)img * 784 + (ty * 2 + r3) * 28 + tx * 2 + c3] = m;
    s3[r3][c3] = m;
  }
  __syncthreads();
  if (tid == 0) {
    const float m = 0.25f * (s3[0][0] + s3[0][1] + s3[1][0] + s3[1][1]);
    dst[98784 + (size_t)img * 196 + ty * 14 + tx] = m;
  }
}

// all 5 scales in one launch; blockIdx.x = concatenated tile index.
// tiles/scale: 196,49,9,4,1 -> cum {0,196,245,254,258,259}
__global__ __launch_bounds__(256) void ssim_all_k(const float* __restrict__ yt,
                                                  const float* __restrict__ yp,
                                                  const float* __restrict__ pyrX,
                                                  const float* __restrict__ pyrY,
                                                  float* __restrict__ acc, GW gw) {
  __shared__ float sX[26][27], sY[26][27];
  __shared__ float sV[5][16][27];
  const int bid = blockIdx.x;
  int s = 0;
  if (bid >= 196) s = 1;
  if (bid >= 245) s = 2;
  if (bid >= 254) s = 3;
  if (bid >= 258) s = 4;
  const int cumA[5]   = {0, 196, 245, 254, 258};
  const int tilesA[5] = {14, 7, 3, 2, 1};
  const int dimsA[5]  = {224, 112, 56, 28, 14};
  const int offsA[5]  = {0, 0, 75264, 94080, 98784};
  const int t = bid - cumA[s];
  const int tiles = tilesA[s];
  const int n = dimsA[s];
  const int m = n - 10;
  const int tid = threadIdx.x;
  const int img = blockIdx.y;
  const int ty0 = (t / tiles) * 16;
  const int tx0 = (t - (t / tiles) * tiles) * 16;
  const float* Xb = ((s == 0) ? yt : pyrX + offsA[s]) + (size_t)img * n * n;
  const float* Yb = ((s == 0) ? yp : pyrY + offsA[s]) + (size_t)img * n * n;

  for (int e = tid; e < 26 * 26; e += 256) {
    const int r = e / 26, c = e - (e / 26) * 26;
    const int gy = ty0 + r, gx = tx0 + c;
    float xv = 0.f, yv = 0.f;
    if (gy < n && gx < n) {
      xv = Xb[(size_t)gy * n + gx];
      yv = Yb[(size_t)gy * n + gx];
    }
    sX[r][c] = xv; sY[r][c] = yv;
  }
  __syncthreads();

  for (int e = tid; e < 16 * 26; e += 256) {
    const int r = e / 26, c = e - (e / 26) * 26;
    float sx = 0.f, sy = 0.f, sxx = 0.f, syy = 0.f, sxy = 0.f;
#pragma unroll
    for (int tt = 0; tt < 11; ++tt) {
      const float xv = sX[r + tt][c];
      const float yv = sY[r + tt][c];
      const float g = gw.g[tt];
      sx += g * xv; sy += g * yv;
      sxx += g * xv * xv; syy += g * yv * yv; sxy += g * xv * yv;
    }
    sV[0][r][c] = sx; sV[1][r][c] = sy;
    sV[2][r][c] = sxx; sV[3][r][c] = syy; sV[4][r][c] = sxy;
  }
  __syncthreads();

  float sv = 0.f, cv = 0.f;
  {
    const int r = tid >> 4, c = tid & 15;
    if (ty0 + r < m && tx0 + c < m) {
      float mu1 = 0.f, mu2 = 0.f, e11 = 0.f, e22 = 0.f, e12 = 0.f;
#pragma unroll
      for (int tt = 0; tt < 11; ++tt) {
        const float g = gw.g[tt];
        mu1 += g * sV[0][r][c + tt];
        mu2 += g * sV[1][r][c + tt];
        e11 += g * sV[2][r][c + tt];
        e22 += g * sV[3][r][c + tt];
        e12 += g * sV[4][r][c + tt];
      }
      const float C1 = 1e-4f, C2 = 9e-4f;
      const float s11 = e11 - mu1 * mu1;
      const float s22 = e22 - mu2 * mu2;
      const float s12 = e12 - mu1 * mu2;
      cv = (2.f * s12 + C2) / (s11 + s22 + C2);
      sv = ((2.f * mu1 * mu2 + C1) / (mu1 * mu1 + mu2 * mu2 + C1)) * cv;
    }
  }
  float tsum = blockSum256(sv);
  if (tid == 0) atomicAdd(acc + SSIM_SLOT(s, 0, img), tsum);
  tsum = blockSum256(cv);
  if (tid == 0) atomicAdd(acc + SSIM_SLOT(s, 1, img), tsum);
}

// ---------------- VGG (fp8 e4m3 path) ----------------

struct PrepArgs {
  const float* w[6];
  int co[6], ci[6];
  int wcum[7];
  unsigned char* zp[6];
  int zH[6], zC[6];
  int zcum[7];
};
__global__ __launch_bounds__(256) void prep_k(PrepArgs a, unsigned char* __restrict__ wdst) {
  const int idx = blockIdx.x * 256 + threadIdx.x;
  if (idx < a.wcum[6]) {
    int L = 0;
    while (idx >= a.wcum[L + 1]) ++L;
    const int r = idx - a.wcum[L];
    const int Cin = a.ci[L];
    const int cin = r % Cin;
    const int t = r / Cin;
    const int tap = t % 9;
    const int cout = t / 9;
    const float v = a.w[L][((size_t)cout * Cin + cin) * 9 + tap] * 8.0f;
    wdst[idx] = (unsigned char)(__builtin_amdgcn_cvt_pk_fp8_f32(v, v, 0, false) & 0xff);
    return;
  }
  const int zi = idx - a.wcum[6];
  if (zi >= a.zcum[6]) return;
  int b = 0;
  while (zi >= a.zcum[b + 1]) ++b;
  const int H = a.zH[b], C = a.zC[b];
  const int rowE = (H + 2) * C;
  const int per = 2 * rowE + 2 * H * C;
  int k = zi - a.zcum[b];
  const int img = k / per;
  const int k0 = k - img * per;
  size_t o;
  if (k0 < rowE) o = k0;
  else if (k0 < 2 * rowE) o = (size_t)(H + 1) * rowE + (k0 - rowE);
  else {
    const int kk = k0 - 2 * rowE;
    const int y = kk / (2 * C) + 1;
    const int r = kk % (2 * C);
    const int x = (r < C) ? 0 : (H + 1);
    const int c = (r < C) ? r : (r - C);
    o = (size_t)y * rowE + (size_t)x * C + c;
  }
  a.zp[b][(size_t)img * (H + 2) * rowE + o] = 0;
}

// layer1 batched: Cin=3 direct fp32 conv, 4 images -> padded NHWC fp8
__global__ __launch_bounds__(256) void conv1_k(
    const float* __restrict__ yt, const float* __restrict__ yp,
    const float* __restrict__ wt, const float* __restrict__ bias,
    unsigned char* __restrict__ out) {
  __shared__ float sIn[3][10][12];
  const int tx = threadIdx.x, ty = threadIdx.y, tz = threadIdx.z;
  const int tid = (tz << 6) | (ty << 3) | tx;
  const int img = blockIdx.z >> 2;
  const int zq = blockIdx.z & 3;
  const float* in = ((img >> 1) ? yp : yt) + (size_t)(img & 1) * 3 * 224 * 224;
  const int x0 = blockIdx.x << 3, y0 = blockIdx.y << 3;
  const int x = x0 + tx, y = y0 + ty;
  int wrow = (zq * 16 + tz * 4) * 27;
  wrow = __builtin_amdgcn_readfirstlane(wrow);

  for (int el = tid; el < 300; el += 256) {
    const int ci = el / 100;
    const int rem = el - ci * 100;
    const int r = rem / 10, cl = rem - r * 10;
    const int gy = y0 - 1 + r, gx = x0 - 1 + cl;
    float v = 0.f;
    if (gy >= 0 && gy < 224 && gx >= 0 && gx < 224)
      v = in[((size_t)ci * 224 + gy) * 224 + gx];
    sIn[ci][r][cl] = v;
  }
  __syncthreads();

  float a0 = 0.f, a1 = 0.f, a2 = 0.f, a3 = 0.f;
#pragma unroll
  for (int ci = 0; ci < 3; ++ci) {
    float xv[9];
#pragma unroll
    for (int ky = 0; ky < 3; ++ky)
#pragma unroll
      for (int kx = 0; kx < 3; ++kx)
        xv[ky * 3 + kx] = sIn[ci][ty + ky][tx + kx];
    const float* wp = wt + wrow + ci * 9;
#pragma unroll
    for (int k = 0; k < 9; ++k) {
      a0 = fmaf(xv[k], wp[k], a0);
      a1 = fmaf(xv[k], wp[27 + k], a1);
      a2 = fmaf(xv[k], wp[54 + k], a2);
      a3 = fmaf(xv[k], wp[81 + k], a3);
    }
  }
  const int coB = zq * 16 + tz * 4;
  const size_t o = (size_t)img * 226 * 226 * 64 + ((size_t)(y + 1) * 226 + (x + 1)) * 64 + coB;
  *(unsigned int*)(out + o) = pk_fp8x4(
      fmaxf(a0 + bias[coB + 0], 0.f), fmaxf(a1 + bias[coB + 1], 0.f),
      fmaxf(a2 + bias[coB + 2], 0.f), fmaxf(a3 + bias[coB + 3], 0.f));
}

// implicit-GEMM conv3x3, batched, fp8 e4m3 via mfma_f32_16x16x32_fp8_fp8.
// Single 28.7KB LDS buffer (4 blocks/CU, m114 inter-block overlap) +
// register prefetch (T14 issue-early/write-late): loads for slab s+1 are
// issued BEFORE the MFMA block of slab s, so L2/HBM latency hides under
// MFMA issue instead of sitting between the two barriers. LDS footprint
// unchanged — this is R1's idea minus the occupancy cost that killed it.
template<int CIN>
__global__ __launch_bounds__(256, 4) void conv_mfma(
    const unsigned char* __restrict__ in, const unsigned char* __restrict__ wtp,
    const float* __restrict__ bias, unsigned char* __restrict__ out,
    int W, int Cout, int rowsPI) {
  constexpr int NSLAB = CIN / 32;
  constexpr int ASTB = 304;
  constexpr int BSTB = 48;
  constexpr int NBRUN = 6 * 66;
  constexpr int NACH = 32 * 18;            // 576
  constexpr int NBCH = NBRUN * 2;          // 792
  constexpr int NAI = (NACH + 255) / 256;  // 3
  constexpr int NBI = (NBCH + 255) / 256;  // 4
  __shared__ unsigned char As[32 * ASTB];
  __shared__ unsigned char Bs[NBRUN * BSTB];

  const int tid = threadIdx.x;
  const int lane = tid & 63;
  const int wave = tid >> 6;
  const int quad = lane >> 4;
  const int lr = lane & 15;
  const int img = blockIdx.y / rowsPI;
  const int y0 = (blockIdx.y - img * rowsPI) * 4;
  const int x0 = blockIdx.x * 64;
  const int cob = blockIdx.z * 32;
  const int Wp = W + 2;
  const int H = rowsPI * 4;
  const unsigned char* inI = in + (size_t)img * (H + 2) * Wp * CIN;
  unsigned char* outI = out + (size_t)img * (H + 2) * Wp * Cout;

  floatx4 acc[2][4];
#pragma unroll
  for (int m = 0; m < 2; ++m)
#pragma unroll
    for (int n = 0; n < 4; ++n) acc[m][n] = (floatx4){0.f, 0.f, 0.f, 0.f};

  const int abase = lr * ASTB + quad * 8;

  // per-thread staging addressing (slab s adds s*32 to the src offsets)
  int asrc[NAI], adst[NAI]; bool aok[NAI];
#pragma unroll
  for (int i = 0; i < NAI; ++i) {
    const int ee = tid + i * 256;
    aok[i] = ee < NACH;
    const int cout = ee / 18;
    const int rem = ee - cout * 18;
    const int tap = rem >> 1;
    const int part = rem & 1;
    asrc[i] = ((cob + cout) * 9 + tap) * CIN + part * 16;
    adst[i] = cout * ASTB + tap * 32 + part * 16;
  }
  int bsrc[NBI], bdst[NBI]; bool bin[NBI], bld[NBI];
#pragma unroll
  for (int i = 0; i < NBI; ++i) {
    const int ee = tid + i * 256;
    bin[i] = ee < NBCH;
    const int part = ee & 1;
    const int run = ee >> 1;
    const int row = run / 66;
    const int px = run - row * 66;
    const int gx = x0 + px;
    bld[i] = bin[i] && (gx < Wp);
    bsrc[i] = ((y0 + row) * Wp + gx) * CIN + part * 16;
    bdst[i] = run * BSTB + part * 16;
  }

  // prologue: issue loads for slab 0
  uint4 pa[NAI], pb[NBI];
#pragma unroll
  for (int i = 0; i < NAI; ++i)
    if (aok[i]) pa[i] = *(const uint4*)(wtp + asrc[i]);
#pragma unroll
  for (int i = 0; i < NBI; ++i) {
    pb[i] = (uint4){0, 0, 0, 0};
    if (bld[i]) pb[i] = *(const uint4*)(inI + (size_t)bsrc[i]);
  }

  for (int s = 0; s < NSLAB; ++s) {
    __syncthreads();   // LDS free (previous slab's MFMA done)
#pragma unroll
    for (int i = 0; i < NAI; ++i)
      if (aok[i]) *(uint4*)(As + adst[i]) = pa[i];
#pragma unroll
    for (int i = 0; i < NBI; ++i)
      if (bin[i]) *(uint4*)(Bs + bdst[i]) = pb[i];
    __syncthreads();

    // issue next slab's loads now; vmcnt drain lands at next iteration's
    // first barrier, so latency overlaps the MFMA block below.
    if (s + 1 < NSLAB) {
      const int so = (s + 1) * 32;
#pragma unroll
      for (int i = 0; i < NAI; ++i)
        if (aok[i]) pa[i] = *(const uint4*)(wtp + asrc[i] + so);
#pragma unroll
      for (int i = 0; i < NBI; ++i)
        if (bld[i]) pb[i] = *(const uint4*)(inI + (size_t)bsrc[i] + so);
    }

#pragma unroll
    for (int dy = 0; dy < 3; ++dy)
#pragma unroll
      for (int dx = 0; dx < 3; ++dx) {
        const int tap = dy * 3 + dx;
        const long af0 = *(const long*)(As + abase + tap * 32);
        const long af1 = *(const long*)(As + abase + 16 * ASTB + tap * 32);
        long bfr[4];
#pragma unroll
        for (int n = 0; n < 4; ++n)
          bfr[n] = *(const long*)(Bs + ((wave + dy) * 66 + n * 16 + lr + dx) * BSTB + quad * 8);
#pragma unroll
        for (int n = 0; n < 4; ++n) {
          acc[0][n] = __builtin_amdgcn_mfma_f32_16x16x32_fp8_fp8(af0, bfr[n], acc[0][n], 0, 0, 0);
          acc[1][n] = __builtin_amdgcn_mfma_f32_16x16x32_fp8_fp8(af1, bfr[n], acc[1][n], 0, 0, 0);
        }
      }
  }

#pragma unroll
  for (int m = 0; m < 2; ++m) {
    const int cb = cob + m * 16 + quad * 4;
#pragma unroll
    for (int n = 0; n < 4; ++n) {
      const int px = x0 + n * 16 + lr;
      if (px < W) {
        const float v0 = fmaxf(acc[m][n].x * 0.125f + bias[cb + 0], 0.f);
        const float v1 = fmaxf(acc[m][n].y * 0.125f + bias[cb + 1], 0.f);
        const float v2 = fmaxf(acc[m][n].z * 0.125f + bias[cb + 2], 0.f);
        const float v3 = fmaxf(acc[m][n].w * 0.125f + bias[cb + 3], 0.f);
        *(unsigned int*)(outI + ((size_t)(y0 + wave + 1) * Wp + px + 1) * Cout + cb) =
            pk_fp8x4(v0, v1, v2, v3);
      }
    }
  }
}

// batched 2x2 maxpool on padded NHWC fp8 (non-negative e4m3: byte max is exact)
__global__ __launch_bounds__(256) void pool_nhwc(const unsigned char* __restrict__ in,
                                                 unsigned char* __restrict__ out,
                                                 int Ho, int Wo, int C) {
  const int per = Ho * Wo * (C / 8);
  const int idx = blockIdx.x * 256 + threadIdx.x;
  if (idx >= 4 * per) return;
  const int img = idx / per;
  const int k = idx - img * per;
  const int c8 = k % (C / 8);
  const int p = k / (C / 8);
  const int x = p % Wo, y = p / Wo;
  const int Wi = 2 * Wo + 2;
  const unsigned char* ib = in + (size_t)img * (2 * Ho + 2) * Wi * C +
                            ((size_t)(2 * y + 1) * Wi + (2 * x + 1)) * C + c8 * 8;
  const uchar8v a = *(const uchar8v*)(ib);
  const uchar8v b = *(const uchar8v*)(ib + C);
  const uchar8v d = *(const uchar8v*)(ib + (size_t)Wi * C);
  const uchar8v e = *(const uchar8v*)(ib + (size_t)Wi * C + C);
  const uchar8v r = __builtin_elementwise_max(__builtin_elementwise_max(a, b),
                                              __builtin_elementwise_max(d, e));
  *(uchar8v*)(out + (size_t)img * (Ho + 2) * (Wo + 2) * C +
              ((size_t)(y + 1) * (Wo + 2) + x + 1) * C + c8 * 8) = r;
}

// perceptual over both batch pairs: F[img][58][58][256] fp8, pairs (0,2),(1,3)
#define FP8D(av, bv, J) { const float dd = __builtin_amdgcn_cvt_f32_fp8((av), (J)) - \
                                           __builtin_amdgcn_cvt_f32_fp8((bv), (J)); \
                          v = fmaf(dd, dd, v); }
__global__ __launch_bounds__(256) void perc_k(const unsigned char* __restrict__ f,
                                              float* __restrict__ acc) {
  const int PER = 56 * 56 * 256 / 8;
  const size_t STR = (size_t)58 * 58 * 256;
  float v = 0.f;
  for (int ch = blockIdx.x * 256 + threadIdx.x; ch < 2 * PER; ch += 256 * 256) {
    const int q = ch / PER;
    const int r = ch - q * PER;
    const int e = r * 8;
    const int c = e & 255;
    const int p = e >> 8;
    const int x = p % 56, y = p / 56;
    const size_t o = ((size_t)(y + 1) * 58 + x + 1) * 256 + c;
    const uint2 a = *(const uint2*)(f + q * STR + o);
    const uint2 b = *(const uint2*)(f + (q + 2) * STR + o);
    FP8D(a.x, b.x, 0) FP8D(a.x, b.x, 1) FP8D(a.x, b.x, 2) FP8D(a.x, b.x, 3)
    FP8D(a.y, b.y, 0) FP8D(a.y, b.y, 1) FP8D(a.y, b.y, 2) FP8D(a.y, b.y, 3)
  }
  const float t = blockSum256(v);
  if (threadIdx.x == 0) atomicAdd(acc + SLOT(ACC_PERC), t);
}

// ---------------- final combine ----------------
__global__ void final_k(const float* __restrict__ acc, float* __restrict__ out) {
  if (threadIdx.x != 0 || blockIdx.x != 0) return;
  const float NPIX = 2.f * 3.f * 224.f * 224.f;
  const float l1 = acc[SLOT(ACC_L1)] / NPIX;
  const float mse = acc[SLOT(ACC_MSE)] / NPIX;
  const float psnr = 40.f + 10.f * log10f(mse);
  const float cm = 1.f / (3.f * 224.f * 224.f);
  const float color = 0.5f * (fabsf(acc[SLOT(ACC_ST0)] - acc[SLOT(ACC_SP0)]) +
                              fabsf(acc[SLOT(ACC_ST1)] - acc[SLOT(ACC_SP1)])) * cm;
  const float ill = acc[SLOT(ACC_HV)] / 669.f + acc[SLOT(ACC_WV)] / 448.f;
  const float expl = acc[SLOT(ACC_EXP)] / 392.f;
  const float spat = acc[SLOT(ACC_SPAT)] / 6272.f;
  const float perc = acc[SLOT(ACC_PERC)] / 1605632.f;
  const float wms[5] = {0.0448f, 0.2856f, 0.3001f, 0.2363f, 0.1333f};
  const int ns[5] = {214, 102, 46, 18, 4};
  float msum = 0.f;
  for (int img = 0; img < 6; ++img) {
    float prod = 1.f;
    for (int s = 0; s < 5; ++s) {
      const float denom = (float)(ns[s] * ns[s]);
      float v = (s == 4) ? acc[SSIM_SLOT(s, 0, img)] / denom
                         : acc[SSIM_SLOT(s, 1, img)] / denom;
      v = fmaxf(v, 0.f);
      prod *= powf(v, wms[s]);
    }
    msum += prod;
  }
  const float msssim = msum / 6.f;
  out[0] = l1 + 0.06f * perc + 0.0083f * psnr + 0.25f * color +
           0.5f * (1.f - msssim) + 0.1f * expl + 0.1f * ill + 0.1f * spat;
}

extern "C" void kernel_launch(void* const* d_in, const int* in_sizes, int n_in,
                              void* d_out, int out_size, void* d_ws, size_t ws_size,
                              hipStream_t stream) {
  const float* yt = (const float*)d_in[0];
  const float* yp = (const float*)d_in[1];
  const float* W7[7]; const float* B7[7];
  for (int i = 0; i < 7; ++i) {
    W7[i] = (const float*)d_in[2 + 2 * i];
    B7[i] = (const float*)d_in[3 + 2 * i];
  }

  char* ws = (char*)d_ws;
  float* acc = (float*)ws;
  size_t off = 16384;
  float* op = (float*)(ws + off); off += 2 * 3136 * 4;
  float* ep = (float*)(ws + off); off += 2 * 3136 * 4;
  auto align256 = [&]() { off = (off + 255) & ~(size_t)255; };
  align256(); unsigned char* C1  = (unsigned char*)(ws + off); off += (size_t)4 * 226 * 226 * 64;
  align256(); unsigned char* T0  = (unsigned char*)(ws + off); off += (size_t)4 * 226 * 226 * 64;
  align256(); unsigned char* Pl1 = (unsigned char*)(ws + off); off += (size_t)4 * 114 * 114 * 64;
  align256(); unsigned char* C3  = (unsigned char*)(ws + off); off += (size_t)4 * 114 * 114 * 128;
  align256(); unsigned char* Pl2 = (unsigned char*)(ws + off); off += (size_t)4 * 58 * 58 * 128;
  align256(); unsigned char* C5  = (unsigned char*)(ws + off); off += (size_t)4 * 58 * 58 * 256;
  align256(); unsigned char* C6  = (unsigned char*)(ws + off); off += (size_t)4 * 58 * 58 * 256;
  align256(); unsigned char* F   = (unsigned char*)(ws + off); off += (size_t)4 * 58 * 58 * 256;
  align256(); unsigned char* WT  = (unsigned char*)(ws + off); off += (size_t)1732608;
  align256(); float* pyrX = (float*)(ws + off); off += (size_t)100000 * 4;
  align256(); float* pyrY = (float*)(ws + off); off += (size_t)100000 * 4;
  if (ws_size < off) return;

  GW gw;
  {
    double vv[11]; double s = 0.0;
    for (int i = 0; i < 11; ++i) { const double c = i - 5.0; vv[i] = exp(-(c * c) / 4.5); s += vv[i]; }
    for (int i = 0; i < 11; ++i) gw.g[i] = (float)(vv[i] / s);
  }

  hipMemsetAsync(acc, 0, 16384, stream);

  // fused prep: weight transform + all border zeroing (one launch)
  const int co[7] = {64, 64, 128, 128, 256, 256, 256};
  const int ci[7] = {3, 64, 64, 128, 128, 256, 256};
  PrepArgs pa;
  size_t wtOff[7];
  {
    int e = 0;
    for (int i = 1; i < 7; ++i) {
      pa.w[i - 1] = W7[i]; pa.co[i - 1] = co[i]; pa.ci[i - 1] = ci[i];
      pa.wcum[i - 1] = e; wtOff[i] = (size_t)e; e += co[i] * 9 * ci[i];
    }
    pa.wcum[6] = e;
    unsigned char* bufs[6] = {C1, Pl1, C3, Pl2, C5, C6};
    const int hh[6] = {224, 112, 112, 56, 56, 56};
    const int cc[6] = {64, 64, 128, 128, 256, 256};
    int z = 0;
    for (int i = 0; i < 6; ++i) {
      pa.zp[i] = bufs[i]; pa.zH[i] = hh[i]; pa.zC[i] = cc[i];
      pa.zcum[i] = z;
      z += 4 * (2 * (hh[i] + 2) * cc[i] + 2 * hh[i] * cc[i]);
    }
    pa.zcum[6] = z;
    const int tot = pa.wcum[6] + z;
    prep_k<<<(tot + 255) / 256, 256, 0, stream>>>(pa, WT);
  }

  basic_stats<<<294, 256, 0, stream>>>(yt, yp, acc);
  pool4_lum_k<<<25, 256, 0, stream>>>(yt, yp, op, ep);
  spat_k<<<25, 256, 0, stream>>>(op, ep, acc);  // includes exposure term

  // MS-SSIM: full pyramid in one launch, then all 5 scales in one launch
  pyramid_k<<<dim3(196, 6, 2), 256, 0, stream>>>(yt, yp, pyrX, pyrY);
  ssim_all_k<<<dim3(259, 6), 256, 0, stream>>>(yt, yp, pyrX, pyrY, acc, gw);

  // VGG19[:16] in fp8, all 4 images per dispatch.
  conv1_k<<<dim3(28, 28, 16), dim3(8, 8, 4), 0, stream>>>(yt, yp, W7[0], B7[0], C1);
  conv_mfma<64> <<<dim3(4, 4 * 56, 2), 256, 0, stream>>>(C1,  WT + wtOff[1], B7[1], T0, 224, 64, 56);
  pool_nhwc<<<(4 * 112 * 112 * 8 + 255) / 256, 256, 0, stream>>>(T0, Pl1, 112, 112, 64);
  conv_mfma<64> <<<dim3(2, 4 * 28, 4), 256, 0, stream>>>(Pl1, WT + wtOff[2], B7[2], C3, 112, 128, 28);
  conv_mfma<128><<<dim3(2, 4 * 28, 4), 256, 0, stream>>>(C3,  WT + wtOff[3], B7[3], T0, 112, 128, 28);
  pool_nhwc<<<(4 * 56 * 56 * 16 + 255) / 256, 256, 0, stream>>>(T0, Pl2, 56, 56, 128);
  conv_mfma<128><<<dim3(1, 4 * 14, 8), 256, 0, stream>>>(Pl2, WT + wtOff[4], B7[4], C5, 56, 256, 14);
  conv_mfma<256><<<dim3(1, 4 * 14, 8), 256, 0, stream>>>(C5,  WT + wtOff[5], B7[5], C6, 56, 256, 14);
  conv_mfma<256><<<dim3(1, 4 * 14, 8), 256, 0, stream>>>(C6,  WT + wtOff[6], B7[6], F,  56, 256, 14);
  perc_k<<<256, 256, 0, stream>>>(F, acc);

  final_k<<<1, 64, 0, stream>>>(acc, (float*)d_out);
}

// Round 5
// 319.463 us; speedup vs baseline: 1.1492x; 1.1492x over previous
//
#include <hip/hip_runtime.h>
#include <cmath>

typedef __attribute__((ext_vector_type(8))) short  short8;
typedef __attribute__((ext_vector_type(4))) float  floatx4;
typedef __attribute__((ext_vector_type(8))) unsigned short ushort8;
typedef __attribute__((ext_vector_type(8))) unsigned char uchar8v;

// Accumulator slots spread 64B apart to avoid same-cacheline atomic serialization.
#define SLOT(i) ((i) * 16)
#define ACC_L1   0
#define ACC_MSE  1
#define ACC_ST0  2
#define ACC_ST1  3
#define ACC_SP0  4
#define ACC_SP1  5
#define ACC_HV   6
#define ACC_WV   7
#define ACC_EXP  8
#define ACC_SPAT 9
#define ACC_PERC 10
#define SSIM_SLOT(scale, cs, img) (256 + ((scale) * 12 + (cs) * 6 + (img)) * 16)

struct GW { float g[11]; };

__device__ __forceinline__ float waveSum(float v) {
#pragma unroll
  for (int o = 32; o > 0; o >>= 1) v += __shfl_down(v, o, 64);
  return v;
}

__device__ __forceinline__ float blockSum256(float v) {
  __shared__ float red[4];
  const int tid = threadIdx.x;
  v = waveSum(v);
  __syncthreads();
  if ((tid & 63) == 0) red[tid >> 6] = v;
  __syncthreads();
  return red[0] + red[1] + red[2] + red[3];
}

// pack 4 floats -> 4 OCP e4m3 bytes (HW cvt, RNE)
__device__ __forceinline__ unsigned int pk_fp8x4(float v0, float v1, float v2, float v3) {
  int p = __builtin_amdgcn_cvt_pk_fp8_f32(v0, v1, 0, false);
  p = __builtin_amdgcn_cvt_pk_fp8_f32(v2, v3, p, true);
  return (unsigned int)p;
}

// ---------------- small loss terms ----------------

// one float4 per thread; grid 294 blocks x 256 = 75264 float4 = full tensor.
__global__ __launch_bounds__(256) void basic_stats(const float* __restrict__ yt,
                                                   const float* __restrict__ yp,
                                                   float* __restrict__ acc) {
  const int i4 = blockIdx.x * 256 + threadIdx.x;  // 0..75263
  const int idx = i4 * 4;
  const float4 t4 = *(const float4*)(yt + idx);
  const float4 p4 = *(const float4*)(yp + idx);
  float l1 = 0.f, mse = 0.f, st0 = 0.f, st1 = 0.f, sp0 = 0.f, sp1 = 0.f, hv = 0.f, wv = 0.f;
#define BTERM(tt, pp) { const float d = (pp) - (tt); const float ad = fabsf(d); \
                        l1 += (ad < 1.f) ? 0.5f * d * d : ad - 0.5f; mse += d * d; }
  BTERM(t4.x, p4.x) BTERM(t4.y, p4.y) BTERM(t4.z, p4.z) BTERM(t4.w, p4.w)
#undef BTERM
  const float ts = t4.x + t4.y + t4.z + t4.w;
  const float ps = p4.x + p4.y + p4.z + p4.w;
  if (i4 < 37632) { st0 = ts; sp0 = ps; } else { st1 = ts; sp1 = ps; }
  const int h = (idx / 224) % 224;
  if (h < 223) {
    const float4 pn = *(const float4*)(yp + idx + 224);
    float d;
    d = pn.x - p4.x; hv += d * d;
    d = pn.y - p4.y; hv += d * d;
    d = pn.z - p4.z; hv += d * d;
    d = pn.w - p4.w; hv += d * d;
  }
  {
    const int w = idx % 224;  // 0,4,...,220
    float d;
    d = p4.y - p4.x; wv += d * d;
    d = p4.z - p4.y; wv += d * d;
    d = p4.w - p4.z; wv += d * d;
    if (w < 220) { d = yp[idx + 4] - p4.w; wv += d * d; }
  }
  float s;
  s = blockSum256(l1);  if (threadIdx.x == 0) atomicAdd(acc + SLOT(ACC_L1), s);
  s = blockSum256(mse); if (threadIdx.x == 0) atomicAdd(acc + SLOT(ACC_MSE), s);
  s = blockSum256(st0); if (threadIdx.x == 0) atomicAdd(acc + SLOT(ACC_ST0), s);
  s = blockSum256(st1); if (threadIdx.x == 0) atomicAdd(acc + SLOT(ACC_ST1), s);
  s = blockSum256(sp0); if (threadIdx.x == 0) atomicAdd(acc + SLOT(ACC_SP0), s);
  s = blockSum256(sp1); if (threadIdx.x == 0) atomicAdd(acc + SLOT(ACC_SP1), s);
  s = blockSum256(hv);  if (threadIdx.x == 0) atomicAdd(acc + SLOT(ACC_HV), s);
  s = blockSum256(wv);  if (threadIdx.x == 0) atomicAdd(acc + SLOT(ACC_WV), s);
}

__global__ __launch_bounds__(256) void pool4_lum_k(const float* __restrict__ yt,
                                                   const float* __restrict__ yp,
                                                   float* __restrict__ op,
                                                   float* __restrict__ ep) {
  const int idx = blockIdx.x * 256 + threadIdx.x;
  if (idx >= 2 * 56 * 56) return;
  const int b = idx / 3136;
  const int rem = idx - b * 3136;
  const int r = rem / 56, cl = rem - r * 56;
  float so = 0.f, se = 0.f;
  for (int c = 0; c < 3; ++c)
#pragma unroll
    for (int dy = 0; dy < 4; ++dy) {
      const size_t off = (((size_t)b * 3 + c) * 224 + (r * 4 + dy)) * 224 + cl * 4;
      const float4 a = *(const float4*)(yt + off);
      const float4 e = *(const float4*)(yp + off);
      so += a.x + a.y + a.z + a.w;
      se += e.x + e.y + e.z + e.w;
    }
  op[idx] = so * (1.f / 48.f);
  ep[idx] = se * (1.f / 48.f);
}

// spat + exposure fused (exposure tile = 4x4 mean of ep; algebraically = 16x16/768 mean)
__global__ __launch_bounds__(256) void spat_k(const float* __restrict__ op,
                                              const float* __restrict__ ep,
                                              float* __restrict__ acc) {
  const int idx = blockIdx.x * 256 + threadIdx.x;
  float v = 0.f;
  if (idx < 6272) {
    const int rem = idx % 3136;
    const int r = rem / 56, cl = rem - r * 56;
    const float oc = op[idx], ec = ep[idx];
    const float ol = (cl > 0)  ? op[idx - 1]  : 0.f;
    const float el = (cl > 0)  ? ep[idx - 1]  : 0.f;
    const float orr = (cl < 55) ? op[idx + 1]  : 0.f;
    const float er  = (cl < 55) ? ep[idx + 1]  : 0.f;
    const float ou = (r > 0)   ? op[idx - 56] : 0.f;
    const float eu = (r > 0)   ? ep[idx - 56] : 0.f;
    const float od = (r < 55)  ? op[idx + 56] : 0.f;
    const float ed = (r < 55)  ? ep[idx + 56] : 0.f;
    float d;
    d = (oc - ol) - (ec - el);   v += d * d;
    d = (oc - orr) - (ec - er);  v += d * d;
    d = (oc - ou) - (ec - eu);   v += d * d;
    d = (oc - od) - (ec - ed);   v += d * d;
  }
  const float t = blockSum256(v);
  if (threadIdx.x == 0) atomicAdd(acc + SLOT(ACC_SPAT), t);
  if (idx < 392) {
    const int b = idx / 196;
    const int rem = idx - b * 196;
    const int py = rem / 14, px = rem - py * 14;
    float ssum = 0.f;
#pragma unroll
    for (int dy = 0; dy < 4; ++dy)
#pragma unroll
      for (int dx = 0; dx < 4; ++dx)
        ssum += ep[b * 3136 + (py * 4 + dy) * 56 + px * 4 + dx];
    const float m = ssum * (1.f / 16.f) - 0.6f;
    atomicAdd(acc + SLOT(ACC_EXP), m * m);
  }
}

// ---------------- MS-SSIM: fused pyramid + single all-scale launch ----------------

__global__ __launch_bounds__(256) void pyramid_k(const float* __restrict__ yt,
                                                 const float* __restrict__ yp,
                                                 float* __restrict__ pyrX,
                                                 float* __restrict__ pyrY) {
  __shared__ float sA[16][17];
  __shared__ float s1[8][9];
  __shared__ float s2[4][5];
  __shared__ float s3[2][3];
  const int tid = threadIdx.x;
  const int img = blockIdx.y;
  const int ty = blockIdx.x / 14, tx = blockIdx.x - ty * 14;
  const float* src = (blockIdx.z ? yp : yt) + (size_t)img * 224 * 224;
  float* dst = blockIdx.z ? pyrY : pyrX;
  const int r = tid >> 4, c = tid & 15;
  sA[r][c] = src[(size_t)(ty * 16 + r) * 224 + tx * 16 + c];
  __syncthreads();
  if (tid < 64) {
    const int r1 = tid >> 3, c1 = tid & 7;
    const float m = 0.25f * (sA[2 * r1][2 * c1] + sA[2 * r1][2 * c1 + 1] +
                             sA[2 * r1 + 1][2 * c1] + sA[2 * r1 + 1][2 * c1 + 1]);
    dst[(size_t)img * 12544 + (ty * 8 + r1) * 112 + tx * 8 + c1] = m;
    s1[r1][c1] = m;
  }
  __syncthreads();
  if (tid < 16) {
    const int r2 = tid >> 2, c2 = tid & 3;
    const float m = 0.25f * (s1[2 * r2][2 * c2] + s1[2 * r2][2 * c2 + 1] +
                             s1[2 * r2 + 1][2 * c2] + s1[2 * r2 + 1][2 * c2 + 1]);
    dst[75264 + (size_t)img * 3136 + (ty * 4 + r2) * 56 + tx * 4 + c2] = m;
    s2[r2][c2] = m;
  }
  __syncthreads();
  if (tid < 4) {
    const int r3 = tid >> 1, c3 = tid & 1;
    const float m = 0.25f * (s2[2 * r3][2 * c3] + s2[2 * r3][2 * c3 + 1] +
                             s2[2 * r3 + 1][2 * c3] + s2[2 * r3 + 1][2 * c3 + 1]);
    dst[94080 + (size_t)img * 784 + (ty * 2 + r3) * 28 + tx * 2 + c3] = m;
    s3[r3][c3] = m;
  }
  __syncthreads();
  if (tid == 0) {
    const float m = 0.25f * (s3[0][0] + s3[0][1] + s3[1][0] + s3[1][1]);
    dst[98784 + (size_t)img * 196 + ty * 14 + tx] = m;
  }
}

// all 5 scales in one launch; tiles/scale 196,49,9,4,1 -> cum {0,196,245,254,258,259}
__global__ __launch_bounds__(256) void ssim_all_k(const float* __restrict__ yt,
                                                  const float* __restrict__ yp,
                                                  const float* __restrict__ pyrX,
                                                  const float* __restrict__ pyrY,
                                                  float* __restrict__ acc, GW gw) {
  __shared__ float sX[26][27], sY[26][27];
  __shared__ float sV[5][16][27];
  const int bid = blockIdx.x;
  int s = 0;
  if (bid >= 196) s = 1;
  if (bid >= 245) s = 2;
  if (bid >= 254) s = 3;
  if (bid >= 258) s = 4;
  const int cumA[5]   = {0, 196, 245, 254, 258};
  const int tilesA[5] = {14, 7, 3, 2, 1};
  const int dimsA[5]  = {224, 112, 56, 28, 14};
  const int offsA[5]  = {0, 0, 75264, 94080, 98784};
  const int t = bid - cumA[s];
  const int tiles = tilesA[s];
  const int n = dimsA[s];
  const int m = n - 10;
  const int tid = threadIdx.x;
  const int img = blockIdx.y;
  const int ty0 = (t / tiles) * 16;
  const int tx0 = (t - (t / tiles) * tiles) * 16;
  const float* Xb = ((s == 0) ? yt : pyrX + offsA[s]) + (size_t)img * n * n;
  const float* Yb = ((s == 0) ? yp : pyrY + offsA[s]) + (size_t)img * n * n;

  for (int e = tid; e < 26 * 26; e += 256) {
    const int r = e / 26, c = e - (e / 26) * 26;
    const int gy = ty0 + r, gx = tx0 + c;
    float xv = 0.f, yv = 0.f;
    if (gy < n && gx < n) {
      xv = Xb[(size_t)gy * n + gx];
      yv = Yb[(size_t)gy * n + gx];
    }
    sX[r][c] = xv; sY[r][c] = yv;
  }
  __syncthreads();

  for (int e = tid; e < 16 * 26; e += 256) {
    const int r = e / 26, c = e - (e / 26) * 26;
    float sx = 0.f, sy = 0.f, sxx = 0.f, syy = 0.f, sxy = 0.f;
#pragma unroll
    for (int tt = 0; tt < 11; ++tt) {
      const float xv = sX[r + tt][c];
      const float yv = sY[r + tt][c];
      const float g = gw.g[tt];
      sx += g * xv; sy += g * yv;
      sxx += g * xv * xv; syy += g * yv * yv; sxy += g * xv * yv;
    }
    sV[0][r][c] = sx; sV[1][r][c] = sy;
    sV[2][r][c] = sxx; sV[3][r][c] = syy; sV[4][r][c] = sxy;
  }
  __syncthreads();

  float sv = 0.f, cv = 0.f;
  {
    const int r = tid >> 4, c = tid & 15;
    if (ty0 + r < m && tx0 + c < m) {
      float mu1 = 0.f, mu2 = 0.f, e11 = 0.f, e22 = 0.f, e12 = 0.f;
#pragma unroll
      for (int tt = 0; tt < 11; ++tt) {
        const float g = gw.g[tt];
        mu1 += g * sV[0][r][c + tt];
        mu2 += g * sV[1][r][c + tt];
        e11 += g * sV[2][r][c + tt];
        e22 += g * sV[3][r][c + tt];
        e12 += g * sV[4][r][c + tt];
      }
      const float C1 = 1e-4f, C2 = 9e-4f;
      const float s11 = e11 - mu1 * mu1;
      const float s22 = e22 - mu2 * mu2;
      const float s12 = e12 - mu1 * mu2;
      cv = (2.f * s12 + C2) / (s11 + s22 + C2);
      sv = ((2.f * mu1 * mu2 + C1) / (mu1 * mu1 + mu2 * mu2 + C1)) * cv;
    }
  }
  float tsum = blockSum256(sv);
  if (tid == 0) atomicAdd(acc + SSIM_SLOT(s, 0, img), tsum);
  tsum = blockSum256(cv);
  if (tid == 0) atomicAdd(acc + SSIM_SLOT(s, 1, img), tsum);
}

// ---------------- VGG (fp8 e4m3 path) ----------------
// ACTIVATION LAYOUT (new, R5): channel-block-major fp8
//   buf[zb][img][H+2][W+2][32]  where zb = channel/32, img in 0..3.
// Rationale [R4 counters]: old NHWC put each block's 32-channel write into a
// 32B strip of every pixel's Cout-byte extent; other strips of the SAME 64B
// line were written by other z-blocks on other XCDs -> WRITE_SIZE 49MB for a
// 13MB tensor (3.8x HBM write amplification). Now every 64B line is written
// entirely by one wave. Slab s of a conv input = plane group s (contiguous).

struct PrepArgs {
  const float* w[6];
  int co[6], ci[6];
  int wcum[7];
  unsigned char* zp[6];
  int zH[6], zC[6];
  int zcum[7];
};
__global__ __launch_bounds__(256) void prep_k(PrepArgs a, unsigned char* __restrict__ wdst) {
  const int idx = blockIdx.x * 256 + threadIdx.x;
  if (idx < a.wcum[6]) {
    int L = 0;
    while (idx >= a.wcum[L + 1]) ++L;
    const int r = idx - a.wcum[L];
    const int Cin = a.ci[L];
    const int cin = r % Cin;
    const int t = r / Cin;
    const int tap = t % 9;
    const int cout = t / 9;
    const float v = a.w[L][((size_t)cout * Cin + cin) * 9 + tap] * 8.0f;
    wdst[idx] = (unsigned char)(__builtin_amdgcn_cvt_pk_fp8_f32(v, v, 0, false) & 0xff);
    return;
  }
  // border zeroing: planes of [H+2][H+2][32]; zC[b]==32, plane count folded
  // into zcum by the host (4 * C/32 planes per buffer).
  const int zi = idx - a.wcum[6];
  if (zi >= a.zcum[6]) return;
  int b = 0;
  while (zi >= a.zcum[b + 1]) ++b;
  const int H = a.zH[b], C = a.zC[b];   // C == 32
  const int rowE = (H + 2) * C;
  const int per = 2 * rowE + 2 * H * C;
  int k = zi - a.zcum[b];
  const int pl = k / per;               // plane index (zb*4+img)
  const int k0 = k - pl * per;
  size_t o;
  if (k0 < rowE) o = k0;
  else if (k0 < 2 * rowE) o = (size_t)(H + 1) * rowE + (k0 - rowE);
  else {
    const int kk = k0 - 2 * rowE;
    const int y = kk / (2 * C) + 1;
    const int r = kk % (2 * C);
    const int x = (r < C) ? 0 : (H + 1);
    const int c = (r < C) ? r : (r - C);
    o = (size_t)y * rowE + (size_t)x * C + c;
  }
  a.zp[b][(size_t)pl * (H + 2) * rowE + o] = 0;
}

// layer1: Cin=3 direct fp32 conv, 4 images. One block owns one 32-channel
// zb for an 8x8 tile -> each thread computes 8 channels, writes 8B; a pixel's
// full 32B chunk is written by the block's 4 waves (same CU/L2).
__global__ __launch_bounds__(256) void conv1_k(
    const float* __restrict__ yt, const float* __restrict__ yp,
    const float* __restrict__ wt, const float* __restrict__ bias,
    unsigned char* __restrict__ out) {
  __shared__ float sIn[3][10][12];
  const int tx = threadIdx.x, ty = threadIdx.y, tz = threadIdx.z;
  const int tid = (tz << 6) | (ty << 3) | tx;
  const int img = blockIdx.z >> 1;
  const int zb = blockIdx.z & 1;
  const float* in = ((img >> 1) ? yp : yt) + (size_t)(img & 1) * 3 * 224 * 224;
  const int x0 = blockIdx.x << 3, y0 = blockIdx.y << 3;
  const int x = x0 + tx, y = y0 + ty;
  int wrow = (zb * 32 + tz * 8) * 27;
  wrow = __builtin_amdgcn_readfirstlane(wrow);

  for (int el = tid; el < 300; el += 256) {
    const int ci = el / 100;
    const int rem = el - ci * 100;
    const int r = rem / 10, cl = rem - r * 10;
    const int gy = y0 - 1 + r, gx = x0 - 1 + cl;
    float v = 0.f;
    if (gy >= 0 && gy < 224 && gx >= 0 && gx < 224)
      v = in[((size_t)ci * 224 + gy) * 224 + gx];
    sIn[ci][r][cl] = v;
  }
  __syncthreads();

  float a[8];
#pragma unroll
  for (int j = 0; j < 8; ++j) a[j] = 0.f;
#pragma unroll
  for (int ci = 0; ci < 3; ++ci) {
    float xv[9];
#pragma unroll
    for (int ky = 0; ky < 3; ++ky)
#pragma unroll
      for (int kx = 0; kx < 3; ++kx)
        xv[ky * 3 + kx] = sIn[ci][ty + ky][tx + kx];
    const float* wp = wt + wrow + ci * 9;
#pragma unroll
    for (int j = 0; j < 8; ++j)
#pragma unroll
      for (int k = 0; k < 9; ++k)
        a[j] = fmaf(xv[k], wp[27 * j + k], a[j]);
  }
  const int coB = zb * 32 + tz * 8;
  float r[8];
#pragma unroll
  for (int j = 0; j < 8; ++j) r[j] = fmaxf(a[j] + bias[coB + j], 0.f);
  const size_t o = (((size_t)(zb * 4 + img) * 226 + (y + 1)) * 226 + (x + 1)) * 32 + tz * 8;
  uint2 rv;
  rv.x = pk_fp8x4(r[0], r[1], r[2], r[3]);
  rv.y = pk_fp8x4(r[4], r[5], r[6], r[7]);
  *(uint2*)(out + o) = rv;
}

// implicit-GEMM conv3x3, batched, fp8 e4m3 via mfma_f32_16x16x32_fp8_fp8.
// R2-exact single-buffer 2-barrier structure (4 blocks/CU, m114 inter-block
// overlap — harness-verified fast; R1/R4 scheduling rewrites both regressed,
// do not reintroduce). Only the global addressing changed for the new
// channel-block-major layout.
template<int CIN>
__global__ __launch_bounds__(256, 4) void conv_mfma(
    const unsigned char* __restrict__ in, const unsigned char* __restrict__ wtp,
    const float* __restrict__ bias, unsigned char* __restrict__ out,
    int W, int rowsPI) {
  constexpr int NSLAB = CIN / 32;
  constexpr int ASTB = 304;
  constexpr int BSTB = 48;
  constexpr int NBRUN = 6 * 66;
  constexpr int NACH = 32 * 18;
  constexpr int NBCH = NBRUN * 2;
  __shared__ unsigned char As[32 * ASTB];
  __shared__ unsigned char Bs[NBRUN * BSTB];

  const int tid = threadIdx.x;
  const int lane = tid & 63;
  const int wave = tid >> 6;
  const int quad = lane >> 4;
  const int lr = lane & 15;
  const int img = blockIdx.y / rowsPI;
  const int y0 = (blockIdx.y - img * rowsPI) * 4;
  const int x0 = blockIdx.x * 64;
  const int cob = blockIdx.z * 32;
  const int Wp = W + 2;
  const int H = rowsPI * 4;
  const size_t IPL = (size_t)(H + 2) * Wp * 32;      // one plane (zb,img)
  const unsigned char* inI = in + (size_t)img * IPL;  // slab s adds s*4*IPL
  unsigned char* outI = out + ((size_t)blockIdx.z * 4 + img) * IPL;

  floatx4 acc[2][4];
#pragma unroll
  for (int m = 0; m < 2; ++m)
#pragma unroll
    for (int n = 0; n < 4; ++n) acc[m][n] = (floatx4){0.f, 0.f, 0.f, 0.f};

  const int abase = lr * ASTB + quad * 8;

  for (int s = 0; s < NSLAB; ++s) {
    __syncthreads();
#pragma unroll
    for (int i = 0; i < (NACH + 255) / 256; ++i) {
      const int ee = tid + i * 256;
      if (ee < NACH) {
        const int cout = ee / 18;
        const int rem = ee - cout * 18;
        const int tap = rem >> 1;
        const int part = rem & 1;
        const uint4 v = *(const uint4*)(wtp + ((size_t)(cob + cout) * 9 + tap) * CIN + s * 32 + part * 16);
        *(uint4*)(As + cout * ASTB + tap * 32 + part * 16) = v;
      }
    }
#pragma unroll
    for (int i = 0; i < (NBCH + 255) / 256; ++i) {
      const int ee = tid + i * 256;
      if (ee < NBCH) {
        const int part = ee & 1;
        const int run = ee >> 1;
        const int row = run / 66;
        const int px = run - row * 66;
        uint4 v = {0, 0, 0, 0};
        const int gx = x0 + px;
        if (gx < Wp)
          v = *(const uint4*)(inI + (size_t)s * 4 * IPL +
                              ((size_t)(y0 + row) * Wp + gx) * 32 + part * 16);
        *(uint4*)(Bs + run * BSTB + part * 16) = v;
      }
    }
    __syncthreads();

#pragma unroll
    for (int dy = 0; dy < 3; ++dy)
#pragma unroll
      for (int dx = 0; dx < 3; ++dx) {
        const int tap = dy * 3 + dx;
        const long af0 = *(const long*)(As + abase + tap * 32);
        const long af1 = *(const long*)(As + abase + 16 * ASTB + tap * 32);
        long bfr[4];
#pragma unroll
        for (int n = 0; n < 4; ++n)
          bfr[n] = *(const long*)(Bs + ((wave + dy) * 66 + n * 16 + lr + dx) * BSTB + quad * 8);
#pragma unroll
        for (int n = 0; n < 4; ++n) {
          acc[0][n] = __builtin_amdgcn_mfma_f32_16x16x32_fp8_fp8(af0, bfr[n], acc[0][n], 0, 0, 0);
          acc[1][n] = __builtin_amdgcn_mfma_f32_16x16x32_fp8_fp8(af1, bfr[n], acc[1][n], 0, 0, 0);
        }
      }
  }

#pragma unroll
  for (int m = 0; m < 2; ++m) {
    const int cb = cob + m * 16 + quad * 4;
#pragma unroll
    for (int n = 0; n < 4; ++n) {
      const int px = x0 + n * 16 + lr;
      if (px < W) {
        const float v0 = fmaxf(acc[m][n].x * 0.125f + bias[cb + 0], 0.f);
        const float v1 = fmaxf(acc[m][n].y * 0.125f + bias[cb + 1], 0.f);
        const float v2 = fmaxf(acc[m][n].z * 0.125f + bias[cb + 2], 0.f);
        const float v3 = fmaxf(acc[m][n].w * 0.125f + bias[cb + 3], 0.f);
        *(unsigned int*)(outI + ((size_t)(y0 + wave + 1) * Wp + px + 1) * 32 +
                         m * 16 + quad * 4) = pk_fp8x4(v0, v1, v2, v3);
      }
    }
  }
}

// batched 2x2 maxpool, channel-block-major fp8 (non-negative e4m3: byte max exact)
__global__ __launch_bounds__(256) void pool_nhwc(const unsigned char* __restrict__ in,
                                                 unsigned char* __restrict__ out,
                                                 int Ho, int Wo, int C) {
  const int per = Ho * Wo * (C / 8);
  const int idx = blockIdx.x * 256 + threadIdx.x;
  if (idx >= 4 * per) return;
  const int img = idx / per;
  const int k = idx - img * per;
  const int c8 = k % (C / 8);
  const int p = k / (C / 8);
  const int x = p % Wo, y = p / Wo;
  const int zb = c8 >> 2;
  const int cw = (c8 & 3) * 8;
  const int Wi = 2 * Wo + 2;
  const unsigned char* ib = in + ((size_t)(zb * 4 + img) * (2 * Ho + 2) * Wi +
                                  (size_t)(2 * y + 1) * Wi + (2 * x + 1)) * 32 + cw;
  const uchar8v a = *(const uchar8v*)(ib);
  const uchar8v b = *(const uchar8v*)(ib + 32);
  const uchar8v d = *(const uchar8v*)(ib + (size_t)Wi * 32);
  const uchar8v e = *(const uchar8v*)(ib + (size_t)Wi * 32 + 32);
  const uchar8v r = __builtin_elementwise_max(__builtin_elementwise_max(a, b),
                                              __builtin_elementwise_max(d, e));
  *(uchar8v*)(out + ((size_t)(zb * 4 + img) * (Ho + 2) * (Wo + 2) +
                     (size_t)(y + 1) * (Wo + 2) + (x + 1)) * 32 + cw) = r;
}

// perceptual: F planes [8 zb][4 img][58][58][32], pairs (img 0,2) and (1,3)
#define FP8D(av, bv, J) { const float dd = __builtin_amdgcn_cvt_f32_fp8((av), (J)) - \
                                           __builtin_amdgcn_cvt_f32_fp8((bv), (J)); \
                          v = fmaf(dd, dd, v); }
__global__ __launch_bounds__(256) void perc_k(const unsigned char* __restrict__ f,
                                              float* __restrict__ acc) {
  const int PER = 56 * 56 * 256 / 8;
  const size_t PL = (size_t)58 * 58 * 32;
  float v = 0.f;
  for (int ch = blockIdx.x * 256 + threadIdx.x; ch < 2 * PER; ch += 256 * 256) {
    const int q = ch / PER;
    const int r = ch - q * PER;
    const int e = r * 8;
    const int c = e & 255;
    const int p = e >> 8;
    const int x = p % 56, y = p / 56;
    const int zb = c >> 5;
    const int cw = c & 31;
    const size_t o = (size_t)(zb * 4 + q) * PL + ((size_t)(y + 1) * 58 + (x + 1)) * 32 + cw;
    const uint2 a = *(const uint2*)(f + o);
    const uint2 b = *(const uint2*)(f + o + 2 * PL);
    FP8D(a.x, b.x, 0) FP8D(a.x, b.x, 1) FP8D(a.x, b.x, 2) FP8D(a.x, b.x, 3)
    FP8D(a.y, b.y, 0) FP8D(a.y, b.y, 1) FP8D(a.y, b.y, 2) FP8D(a.y, b.y, 3)
  }
  const float t = blockSum256(v);
  if (threadIdx.x == 0) atomicAdd(acc + SLOT(ACC_PERC), t);
}

// ---------------- final combine ----------------
__global__ void final_k(const float* __restrict__ acc, float* __restrict__ out) {
  if (threadIdx.x != 0 || blockIdx.x != 0) return;
  const float NPIX = 2.f * 3.f * 224.f * 224.f;
  const float l1 = acc[SLOT(ACC_L1)] / NPIX;
  const float mse = acc[SLOT(ACC_MSE)] / NPIX;
  const float psnr = 40.f + 10.f * log10f(mse);
  const float cm = 1.f / (3.f * 224.f * 224.f);
  const float color = 0.5f * (fabsf(acc[SLOT(ACC_ST0)] - acc[SLOT(ACC_SP0)]) +
                              fabsf(acc[SLOT(ACC_ST1)] - acc[SLOT(ACC_SP1)])) * cm;
  const float ill = acc[SLOT(ACC_HV)] / 669.f + acc[SLOT(ACC_WV)] / 448.f;
  const float expl = acc[SLOT(ACC_EXP)] / 392.f;
  const float spat = acc[SLOT(ACC_SPAT)] / 6272.f;
  const float perc = acc[SLOT(ACC_PERC)] / 1605632.f;
  const float wms[5] = {0.0448f, 0.2856f, 0.3001f, 0.2363f, 0.1333f};
  const int ns[5] = {214, 102, 46, 18, 4};
  float msum = 0.f;
  for (int img = 0; img < 6; ++img) {
    float prod = 1.f;
    for (int s = 0; s < 5; ++s) {
      const float denom = (float)(ns[s] * ns[s]);
      float v = (s == 4) ? acc[SSIM_SLOT(s, 0, img)] / denom
                         : acc[SSIM_SLOT(s, 1, img)] / denom;
      v = fmaxf(v, 0.f);
      prod *= powf(v, wms[s]);
    }
    msum += prod;
  }
  const float msssim = msum / 6.f;
  out[0] = l1 + 0.06f * perc + 0.0083f * psnr + 0.25f * color +
           0.5f * (1.f - msssim) + 0.1f * expl + 0.1f * ill + 0.1f * spat;
}

extern "C" void kernel_launch(void* const* d_in, const int* in_sizes, int n_in,
                              void* d_out, int out_size, void* d_ws, size_t ws_size,
                              hipStream_t stream) {
  const float* yt = (const float*)d_in[0];
  const float* yp = (const float*)d_in[1];
  const float* W7[7]; const float* B7[7];
  for (int i = 0; i < 7; ++i) {
    W7[i] = (const float*)d_in[2 + 2 * i];
    B7[i] = (const float*)d_in[3 + 2 * i];
  }

  char* ws = (char*)d_ws;
  float* acc = (float*)ws;
  size_t off = 16384;
  float* op = (float*)(ws + off); off += 2 * 3136 * 4;
  float* ep = (float*)(ws + off); off += 2 * 3136 * 4;
  auto align256 = [&]() { off = (off + 255) & ~(size_t)255; };
  align256(); unsigned char* C1  = (unsigned char*)(ws + off); off += (size_t)4 * 226 * 226 * 64;
  align256(); unsigned char* T0  = (unsigned char*)(ws + off); off += (size_t)4 * 226 * 226 * 64;
  align256(); unsigned char* Pl1 = (unsigned char*)(ws + off); off += (size_t)4 * 114 * 114 * 64;
  align256(); unsigned char* C3  = (unsigned char*)(ws + off); off += (size_t)4 * 114 * 114 * 128;
  align256(); unsigned char* Pl2 = (unsigned char*)(ws + off); off += (size_t)4 * 58 * 58 * 128;
  align256(); unsigned char* C5  = (unsigned char*)(ws + off); off += (size_t)4 * 58 * 58 * 256;
  align256(); unsigned char* C6  = (unsigned char*)(ws + off); off += (size_t)4 * 58 * 58 * 256;
  align256(); unsigned char* F   = (unsigned char*)(ws + off); off += (size_t)4 * 58 * 58 * 256;
  align256(); unsigned char* WT  = (unsigned char*)(ws + off); off += (size_t)1732608;
  align256(); float* pyrX = (float*)(ws + off); off += (size_t)100000 * 4;
  align256(); float* pyrY = (float*)(ws + off); off += (size_t)100000 * 4;
  if (ws_size < off) return;

  GW gw;
  {
    double vv[11]; double s = 0.0;
    for (int i = 0; i < 11; ++i) { const double c = i - 5.0; vv[i] = exp(-(c * c) / 4.5); s += vv[i]; }
    for (int i = 0; i < 11; ++i) gw.g[i] = (float)(vv[i] / s);
  }

  hipMemsetAsync(acc, 0, 16384, stream);

  // fused prep: weight transform + all border zeroing (one launch).
  // Zero planes are [4*C/32] x [H+2][H+2][32] per buffer (layout change).
  const int co[7] = {64, 64, 128, 128, 256, 256, 256};
  const int ci[7] = {3, 64, 64, 128, 128, 256, 256};
  PrepArgs pa;
  size_t wtOff[7];
  {
    int e = 0;
    for (int i = 1; i < 7; ++i) {
      pa.w[i - 1] = W7[i]; pa.co[i - 1] = co[i]; pa.ci[i - 1] = ci[i];
      pa.wcum[i - 1] = e; wtOff[i] = (size_t)e; e += co[i] * 9 * ci[i];
    }
    pa.wcum[6] = e;
    unsigned char* bufs[6] = {C1, Pl1, C3, Pl2, C5, C6};
    const int hh[6] = {224, 112, 112, 56, 56, 56};
    const int cc[6] = {64, 64, 128, 128, 256, 256};
    int z = 0;
    for (int i = 0; i < 6; ++i) {
      pa.zp[i] = bufs[i]; pa.zH[i] = hh[i]; pa.zC[i] = 32;
      pa.zcum[i] = z;
      z += (4 * cc[i] / 32) * (2 * (hh[i] + 2) * 32 + 2 * hh[i] * 32);
    }
    pa.zcum[6] = z;
    const int tot = pa.wcum[6] + z;
    prep_k<<<(tot + 255) / 256, 256, 0, stream>>>(pa, WT);
  }

  basic_stats<<<294, 256, 0, stream>>>(yt, yp, acc);
  pool4_lum_k<<<25, 256, 0, stream>>>(yt, yp, op, ep);
  spat_k<<<25, 256, 0, stream>>>(op, ep, acc);  // includes exposure term

  // MS-SSIM: full pyramid in one launch, then all 5 scales in one launch
  pyramid_k<<<dim3(196, 6, 2), 256, 0, stream>>>(yt, yp, pyrX, pyrY);
  ssim_all_k<<<dim3(259, 6), 256, 0, stream>>>(yt, yp, pyrX, pyrY, acc, gw);

  // VGG19[:16] in fp8, all 4 images per dispatch.
  conv1_k<<<dim3(28, 28, 8), dim3(8, 8, 4), 0, stream>>>(yt, yp, W7[0], B7[0], C1);
  conv_mfma<64> <<<dim3(4, 4 * 56, 2), 256, 0, stream>>>(C1,  WT + wtOff[1], B7[1], T0, 224, 56);
  pool_nhwc<<<(4 * 112 * 112 * 8 + 255) / 256, 256, 0, stream>>>(T0, Pl1, 112, 112, 64);
  conv_mfma<64> <<<dim3(2, 4 * 28, 4), 256, 0, stream>>>(Pl1, WT + wtOff[2], B7[2], C3, 112, 28);
  conv_mfma<128><<<dim3(2, 4 * 28, 4), 256, 0, stream>>>(C3,  WT + wtOff[3], B7[3], T0, 112, 28);
  pool_nhwc<<<(4 * 56 * 56 * 16 + 255) / 256, 256, 0, stream>>>(T0, Pl2, 56, 56, 128);
  conv_mfma<128><<<dim3(1, 4 * 14, 8), 256, 0, stream>>>(Pl2, WT + wtOff[4], B7[4], C5, 56, 14);
  conv_mfma<256><<<dim3(1, 4 * 14, 8), 256, 0, stream>>>(C5,  WT + wtOff[5], B7[5], C6, 56, 14);
  conv_mfma<256><<<dim3(1, 4 * 14, 8), 256, 0, stream>>>(C6,  WT + wtOff[6], B7[6], F,  56, 14);
  perc_k<<<256, 256, 0, stream>>>(F, acc);

  final_k<<<1, 64, 0, stream>>>(acc, (float*)d_out);
}

// Round 6
// 301.843 us; speedup vs baseline: 1.2163x; 1.0584x over previous
//
#include <hip/hip_runtime.h>
#include <cmath>

typedef __attribute__((ext_vector_type(8))) short  short8;
typedef __attribute__((ext_vector_type(4))) float  floatx4;
typedef __attribute__((ext_vector_type(8))) unsigned short ushort8;
typedef __attribute__((ext_vector_type(8))) unsigned char uchar8v;

// Accumulator slots spread 64B apart to avoid same-cacheline atomic serialization.
#define SLOT(i) ((i) * 16)
#define ACC_L1   0
#define ACC_MSE  1
#define ACC_ST0  2
#define ACC_ST1  3
#define ACC_SP0  4
#define ACC_SP1  5
#define ACC_HV   6
#define ACC_WV   7
#define ACC_EXP  8
#define ACC_SPAT 9
#define ACC_PERC 10
#define SSIM_SLOT(scale, cs, img) (256 + ((scale) * 12 + (cs) * 6 + (img)) * 16)

struct GW { float g[11]; };

__device__ __forceinline__ float waveSum(float v) {
#pragma unroll
  for (int o = 32; o > 0; o >>= 1) v += __shfl_down(v, o, 64);
  return v;
}

__device__ __forceinline__ float blockSum256(float v) {
  __shared__ float red[4];
  const int tid = threadIdx.x;
  v = waveSum(v);
  __syncthreads();
  if ((tid & 63) == 0) red[tid >> 6] = v;
  __syncthreads();
  return red[0] + red[1] + red[2] + red[3];
}

// pack 4 floats -> 4 OCP e4m3 bytes (HW cvt, RNE)
__device__ __forceinline__ unsigned int pk_fp8x4(float v0, float v1, float v2, float v3) {
  int p = __builtin_amdgcn_cvt_pk_fp8_f32(v0, v1, 0, false);
  p = __builtin_amdgcn_cvt_pk_fp8_f32(v2, v3, p, true);
  return (unsigned int)p;
}

// ---------------- mega front-section kernel ----------------
// Fuses (block-range dispatch; all writes disjoint, no cross-block deps):
//   [0, nPrep)   prep: weight->fp8 transform + border zeroing
//   [.., +294)   basic_stats (l1/mse/color sums/ill)
//   [.., +2352)  MS-SSIM pyramid (all 4 levels per 16x16 tile)
//   [.., +32)    pooled-luminance tile + spat + exposure (pool recomputed
//                per-block with halo, bit-identical arithmetic to the old
//                pool4_lum; op/ep buffers eliminated)
//   [.., +6272)  conv1 (Cin=3 fp32 direct conv; reads raw W0, writes C1
//                interior; prep writes only C1 borders -> disjoint)

struct PrepArgs {
  const float* w[6];
  int co[6], ci[6];
  int wcum[7];
  unsigned char* zp[6];
  int zH[6], zC[6];
  int zcum[7];
};

struct MegaArgs {
  PrepArgs pa;
  unsigned char* wdst;
  const float* w0;
  const float* b0;
  unsigned char* c1;
  float* pyrX;
  float* pyrY;
  float* acc;
  int nPrep, nBasic, nPyr, nPS;
};

__global__ __launch_bounds__(256) void mega_k(MegaArgs A,
                                              const float* __restrict__ yt,
                                              const float* __restrict__ yp) {
  __shared__ float smem[684];
  const int tid = threadIdx.x;
  int bid = blockIdx.x;

  // ---------- prep ----------
  if (bid < A.nPrep) {
    const int idx = bid * 256 + tid;
    const PrepArgs& a = A.pa;
    if (idx < a.wcum[6]) {
      int L = 0;
      while (idx >= a.wcum[L + 1]) ++L;
      const int r = idx - a.wcum[L];
      const int Cin = a.ci[L];
      const int cin = r % Cin;
      const int t = r / Cin;
      const int tap = t % 9;
      const int cout = t / 9;
      const float v = a.w[L][((size_t)cout * Cin + cin) * 9 + tap] * 8.0f;
      A.wdst[idx] = (unsigned char)(__builtin_amdgcn_cvt_pk_fp8_f32(v, v, 0, false) & 0xff);
      return;
    }
    const int zi = idx - a.wcum[6];
    if (zi >= a.zcum[6]) return;
    int b = 0;
    while (zi >= a.zcum[b + 1]) ++b;
    const int H = a.zH[b], C = a.zC[b];   // C == 32
    const int rowE = (H + 2) * C;
    const int per = 2 * rowE + 2 * H * C;
    int k = zi - a.zcum[b];
    const int pl = k / per;               // plane index (zb*4+img)
    const int k0 = k - pl * per;
    size_t o;
    if (k0 < rowE) o = k0;
    else if (k0 < 2 * rowE) o = (size_t)(H + 1) * rowE + (k0 - rowE);
    else {
      const int kk = k0 - 2 * rowE;
      const int y = kk / (2 * C) + 1;
      const int r = kk % (2 * C);
      const int x = (r < C) ? 0 : (H + 1);
      const int c = (r < C) ? r : (r - C);
      o = (size_t)y * rowE + (size_t)x * C + c;
    }
    a.zp[b][(size_t)pl * (H + 2) * rowE + o] = 0;
    return;
  }
  bid -= A.nPrep;

  // ---------- basic_stats ----------
  if (bid < A.nBasic) {
    float* acc = A.acc;
    const int i4 = bid * 256 + tid;  // 0..75263
    const int idx = i4 * 4;
    const float4 t4 = *(const float4*)(yt + idx);
    const float4 p4 = *(const float4*)(yp + idx);
    float l1 = 0.f, mse = 0.f, st0 = 0.f, st1 = 0.f, sp0 = 0.f, sp1 = 0.f, hv = 0.f, wv = 0.f;
#define BTERM(tt, pp) { const float d = (pp) - (tt); const float ad = fabsf(d); \
                        l1 += (ad < 1.f) ? 0.5f * d * d : ad - 0.5f; mse += d * d; }
    BTERM(t4.x, p4.x) BTERM(t4.y, p4.y) BTERM(t4.z, p4.z) BTERM(t4.w, p4.w)
#undef BTERM
    const float ts = t4.x + t4.y + t4.z + t4.w;
    const float ps = p4.x + p4.y + p4.z + p4.w;
    if (i4 < 37632) { st0 = ts; sp0 = ps; } else { st1 = ts; sp1 = ps; }
    const int h = (idx / 224) % 224;
    if (h < 223) {
      const float4 pn = *(const float4*)(yp + idx + 224);
      float d;
      d = pn.x - p4.x; hv += d * d;
      d = pn.y - p4.y; hv += d * d;
      d = pn.z - p4.z; hv += d * d;
      d = pn.w - p4.w; hv += d * d;
    }
    {
      const int w = idx % 224;
      float d;
      d = p4.y - p4.x; wv += d * d;
      d = p4.z - p4.y; wv += d * d;
      d = p4.w - p4.z; wv += d * d;
      if (w < 220) { d = yp[idx + 4] - p4.w; wv += d * d; }
    }
    float s;
    s = blockSum256(l1);  if (tid == 0) atomicAdd(acc + SLOT(ACC_L1), s);
    s = blockSum256(mse); if (tid == 0) atomicAdd(acc + SLOT(ACC_MSE), s);
    s = blockSum256(st0); if (tid == 0) atomicAdd(acc + SLOT(ACC_ST0), s);
    s = blockSum256(st1); if (tid == 0) atomicAdd(acc + SLOT(ACC_ST1), s);
    s = blockSum256(sp0); if (tid == 0) atomicAdd(acc + SLOT(ACC_SP0), s);
    s = blockSum256(sp1); if (tid == 0) atomicAdd(acc + SLOT(ACC_SP1), s);
    s = blockSum256(hv);  if (tid == 0) atomicAdd(acc + SLOT(ACC_HV), s);
    s = blockSum256(wv);  if (tid == 0) atomicAdd(acc + SLOT(ACC_WV), s);
    return;
  }
  bid -= A.nBasic;

  // ---------- pyramid ----------
  if (bid < A.nPyr) {
    float (*sA)[17] = (float(*)[17])smem;          // 272
    float (*s1)[9]  = (float(*)[9])(smem + 272);   // 72
    float (*s2)[5]  = (float(*)[5])(smem + 344);   // 20
    float (*s3)[3]  = (float(*)[3])(smem + 364);   // 6
    const int tile = bid % 196;
    const int img = (bid / 196) % 6;
    const int zt = bid / (196 * 6);
    const int ty = tile / 14, tx = tile - ty * 14;
    const float* src = (zt ? yp : yt) + (size_t)img * 224 * 224;
    float* dst = zt ? A.pyrY : A.pyrX;
    const int r = tid >> 4, c = tid & 15;
    sA[r][c] = src[(size_t)(ty * 16 + r) * 224 + tx * 16 + c];
    __syncthreads();
    if (tid < 64) {
      const int r1 = tid >> 3, c1 = tid & 7;
      const float m = 0.25f * (sA[2 * r1][2 * c1] + sA[2 * r1][2 * c1 + 1] +
                               sA[2 * r1 + 1][2 * c1] + sA[2 * r1 + 1][2 * c1 + 1]);
      dst[(size_t)img * 12544 + (ty * 8 + r1) * 112 + tx * 8 + c1] = m;
      s1[r1][c1] = m;
    }
    __syncthreads();
    if (tid < 16) {
      const int r2 = tid >> 2, c2 = tid & 3;
      const float m = 0.25f * (s1[2 * r2][2 * c2] + s1[2 * r2][2 * c2 + 1] +
                               s1[2 * r2 + 1][2 * c2] + s1[2 * r2 + 1][2 * c2 + 1]);
      dst[75264 + (size_t)img * 3136 + (ty * 4 + r2) * 56 + tx * 4 + c2] = m;
      s2[r2][c2] = m;
    }
    __syncthreads();
    if (tid < 4) {
      const int r3 = tid >> 1, c3 = tid & 1;
      const float m = 0.25f * (s2[2 * r3][2 * c3] + s2[2 * r3][2 * c3 + 1] +
                               s2[2 * r3 + 1][2 * c3] + s2[2 * r3 + 1][2 * c3 + 1]);
      dst[94080 + (size_t)img * 784 + (ty * 2 + r3) * 28 + tx * 2 + c3] = m;
      s3[r3][c3] = m;
    }
    __syncthreads();
    if (tid == 0) {
      const float m = 0.25f * (s3[0][0] + s3[0][1] + s3[1][0] + s3[1][1]);
      dst[98784 + (size_t)img * 196 + ty * 14 + tx] = m;
    }
    return;
  }
  bid -= A.nPyr;

  // ---------- pooled-lum tile + spat + exposure ----------
  if (bid < A.nPS) {
    float* acc = A.acc;
    float (*sOp)[19] = (float(*)[19])smem;          // 18x19
    float (*sEp)[19] = (float(*)[19])(smem + 342);  // 18x19
    const int b = bid >> 4;                 // img
    const int tq = bid & 15;
    const int ty0 = (tq >> 2) * 16, tx0 = (tq & 3) * 16;
    for (int e = tid; e < 18 * 18; e += 256) {
      const int r = e / 18, c = e - (e / 18) * 18;
      const int gy = ty0 - 1 + r, gx = tx0 - 1 + c;
      float vo = 0.f, ve = 0.f;
      if (gy >= 0 && gy < 56 && gx >= 0 && gx < 56) {
        float so = 0.f, se = 0.f;
        for (int ch = 0; ch < 3; ++ch)
#pragma unroll
          for (int dy = 0; dy < 4; ++dy) {
            const size_t off = (((size_t)b * 3 + ch) * 224 + (gy * 4 + dy)) * 224 + gx * 4;
            const float4 a = *(const float4*)(yt + off);
            const float4 ee = *(const float4*)(yp + off);
            so += a.x + a.y + a.z + a.w;
            se += ee.x + ee.y + ee.z + ee.w;
          }
        vo = so * (1.f / 48.f);
        ve = se * (1.f / 48.f);
      }
      sOp[r][c] = vo; sEp[r][c] = ve;
    }
    __syncthreads();
    float v = 0.f;
    {
      const int r = tid >> 4, c = tid & 15;
      const int gy = ty0 + r, gx = tx0 + c;
      if (gy < 56 && gx < 56) {
        const float oc = sOp[r + 1][c + 1], ec = sEp[r + 1][c + 1];
        const float ol = sOp[r + 1][c],     el = sEp[r + 1][c];
        const float orr = sOp[r + 1][c + 2], er = sEp[r + 1][c + 2];
        const float ou = sOp[r][c + 1],     eu = sEp[r][c + 1];
        const float od = sOp[r + 2][c + 1], ed = sEp[r + 2][c + 1];
        float d;
        d = (oc - ol) - (ec - el);   v += d * d;
        d = (oc - orr) - (ec - er);  v += d * d;
        d = (oc - ou) - (ec - eu);   v += d * d;
        d = (oc - od) - (ec - ed);   v += d * d;
      }
    }
    const float t = blockSum256(v);
    if (tid == 0) atomicAdd(acc + SLOT(ACC_SPAT), t);
    if (tid < 16) {
      const int ey = tid >> 2, ex = tid & 3;
      if (ty0 + 4 * ey < 56 && tx0 + 4 * ex < 56) {
        float ssum = 0.f;
#pragma unroll
        for (int dy = 0; dy < 4; ++dy)
#pragma unroll
          for (int dx = 0; dx < 4; ++dx)
            ssum += sEp[4 * ey + dy + 1][4 * ex + dx + 1];
        const float m = ssum * (1.f / 16.f) - 0.6f;
        atomicAdd(acc + SLOT(ACC_EXP), m * m);
      }
    }
    return;
  }
  bid -= A.nPS;

  // ---------- conv1 ----------
  {
    float (*sIn)[10][12] = (float(*)[10][12])smem;
    const int zf = bid / 784;
    const int rem = bid - zf * 784;
    const int by = rem / 28, bx = rem - by * 28;
    const int tx = tid & 7, ty = (tid >> 3) & 7, tz = tid >> 6;
    const int img = zf >> 1;
    const int zb = zf & 1;
    const float* in = ((img >> 1) ? yp : yt) + (size_t)(img & 1) * 3 * 224 * 224;
    const int x0 = bx << 3, y0 = by << 3;
    const int x = x0 + tx, y = y0 + ty;
    int wrow = (zb * 32 + tz * 8) * 27;
    wrow = __builtin_amdgcn_readfirstlane(wrow);

    for (int el = tid; el < 300; el += 256) {
      const int ci = el / 100;
      const int r2 = el - ci * 100;
      const int r = r2 / 10, cl = r2 - r * 10;
      const int gy = y0 - 1 + r, gx = x0 - 1 + cl;
      float v = 0.f;
      if (gy >= 0 && gy < 224 && gx >= 0 && gx < 224)
        v = in[((size_t)ci * 224 + gy) * 224 + gx];
      sIn[ci][r][cl] = v;
    }
    __syncthreads();

    float a[8];
#pragma unroll
    for (int j = 0; j < 8; ++j) a[j] = 0.f;
#pragma unroll
    for (int ci = 0; ci < 3; ++ci) {
      float xv[9];
#pragma unroll
      for (int ky = 0; ky < 3; ++ky)
#pragma unroll
        for (int kx = 0; kx < 3; ++kx)
          xv[ky * 3 + kx] = sIn[ci][ty + ky][tx + kx];
      const float* wp = A.w0 + wrow + ci * 9;
#pragma unroll
      for (int j = 0; j < 8; ++j)
#pragma unroll
        for (int k = 0; k < 9; ++k)
          a[j] = fmaf(xv[k], wp[27 * j + k], a[j]);
    }
    const int coB = zb * 32 + tz * 8;
    float r[8];
#pragma unroll
    for (int j = 0; j < 8; ++j) r[j] = fmaxf(a[j] + A.b0[coB + j], 0.f);
    const size_t o = (((size_t)(zb * 4 + img) * 226 + (y + 1)) * 226 + (x + 1)) * 32 + tz * 8;
    uint2 rv;
    rv.x = pk_fp8x4(r[0], r[1], r[2], r[3]);
    rv.y = pk_fp8x4(r[4], r[5], r[6], r[7]);
    *(uint2*)(A.c1 + o) = rv;
  }
}

// ---------------- MS-SSIM all-scale kernel ----------------
// tiles/scale 196,49,9,4,1 -> cum {0,196,245,254,258,259}
__global__ __launch_bounds__(256) void ssim_all_k(const float* __restrict__ yt,
                                                  const float* __restrict__ yp,
                                                  const float* __restrict__ pyrX,
                                                  const float* __restrict__ pyrY,
                                                  float* __restrict__ acc, GW gw) {
  __shared__ float sX[26][27], sY[26][27];
  __shared__ float sV[5][16][27];
  const int bid = blockIdx.x;
  int s = 0;
  if (bid >= 196) s = 1;
  if (bid >= 245) s = 2;
  if (bid >= 254) s = 3;
  if (bid >= 258) s = 4;
  const int cumA[5]   = {0, 196, 245, 254, 258};
  const int tilesA[5] = {14, 7, 3, 2, 1};
  const int dimsA[5]  = {224, 112, 56, 28, 14};
  const int offsA[5]  = {0, 0, 75264, 94080, 98784};
  const int t = bid - cumA[s];
  const int tiles = tilesA[s];
  const int n = dimsA[s];
  const int m = n - 10;
  const int tid = threadIdx.x;
  const int img = blockIdx.y;
  const int ty0 = (t / tiles) * 16;
  const int tx0 = (t - (t / tiles) * tiles) * 16;
  const float* Xb = ((s == 0) ? yt : pyrX + offsA[s]) + (size_t)img * n * n;
  const float* Yb = ((s == 0) ? yp : pyrY + offsA[s]) + (size_t)img * n * n;

  for (int e = tid; e < 26 * 26; e += 256) {
    const int r = e / 26, c = e - (e / 26) * 26;
    const int gy = ty0 + r, gx = tx0 + c;
    float xv = 0.f, yv = 0.f;
    if (gy < n && gx < n) {
      xv = Xb[(size_t)gy * n + gx];
      yv = Yb[(size_t)gy * n + gx];
    }
    sX[r][c] = xv; sY[r][c] = yv;
  }
  __syncthreads();

  for (int e = tid; e < 16 * 26; e += 256) {
    const int r = e / 26, c = e - (e / 26) * 26;
    float sx = 0.f, sy = 0.f, sxx = 0.f, syy = 0.f, sxy = 0.f;
#pragma unroll
    for (int tt = 0; tt < 11; ++tt) {
      const float xv = sX[r + tt][c];
      const float yv = sY[r + tt][c];
      const float g = gw.g[tt];
      sx += g * xv; sy += g * yv;
      sxx += g * xv * xv; syy += g * yv * yv; sxy += g * xv * yv;
    }
    sV[0][r][c] = sx; sV[1][r][c] = sy;
    sV[2][r][c] = sxx; sV[3][r][c] = syy; sV[4][r][c] = sxy;
  }
  __syncthreads();

  float sv = 0.f, cv = 0.f;
  {
    const int r = tid >> 4, c = tid & 15;
    if (ty0 + r < m && tx0 + c < m) {
      float mu1 = 0.f, mu2 = 0.f, e11 = 0.f, e22 = 0.f, e12 = 0.f;
#pragma unroll
      for (int tt = 0; tt < 11; ++tt) {
        const float g = gw.g[tt];
        mu1 += g * sV[0][r][c + tt];
        mu2 += g * sV[1][r][c + tt];
        e11 += g * sV[2][r][c + tt];
        e22 += g * sV[3][r][c + tt];
        e12 += g * sV[4][r][c + tt];
      }
      const float C1 = 1e-4f, C2 = 9e-4f;
      const float s11 = e11 - mu1 * mu1;
      const float s22 = e22 - mu2 * mu2;
      const float s12 = e12 - mu1 * mu2;
      cv = (2.f * s12 + C2) / (s11 + s22 + C2);
      sv = ((2.f * mu1 * mu2 + C1) / (mu1 * mu1 + mu2 * mu2 + C1)) * cv;
    }
  }
  float tsum = blockSum256(sv);
  if (tid == 0) atomicAdd(acc + SSIM_SLOT(s, 0, img), tsum);
  tsum = blockSum256(cv);
  if (tid == 0) atomicAdd(acc + SSIM_SLOT(s, 1, img), tsum);
}

// ---------------- VGG conv (fp8 e4m3, channel-block-major) ----------------
// Activation layout: buf[zb][img][H+2][W+2][32]. R2-exact single-buffer
// 2-barrier conv structure (4 blocks/CU; R1/R4 rewrites both regressed).
template<int CIN>
__global__ __launch_bounds__(256, 4) void conv_mfma(
    const unsigned char* __restrict__ in, const unsigned char* __restrict__ wtp,
    const float* __restrict__ bias, unsigned char* __restrict__ out,
    int W, int rowsPI) {
  constexpr int NSLAB = CIN / 32;
  constexpr int ASTB = 304;
  constexpr int BSTB = 48;
  constexpr int NBRUN = 6 * 66;
  constexpr int NACH = 32 * 18;
  constexpr int NBCH = NBRUN * 2;
  __shared__ unsigned char As[32 * ASTB];
  __shared__ unsigned char Bs[NBRUN * BSTB];

  const int tid = threadIdx.x;
  const int lane = tid & 63;
  const int wave = tid >> 6;
  const int quad = lane >> 4;
  const int lr = lane & 15;
  const int img = blockIdx.y / rowsPI;
  const int y0 = (blockIdx.y - img * rowsPI) * 4;
  const int x0 = blockIdx.x * 64;
  const int cob = blockIdx.z * 32;
  const int Wp = W + 2;
  const int H = rowsPI * 4;
  const size_t IPL = (size_t)(H + 2) * Wp * 32;      // one plane (zb,img)
  const unsigned char* inI = in + (size_t)img * IPL;  // slab s adds s*4*IPL
  unsigned char* outI = out + ((size_t)blockIdx.z * 4 + img) * IPL;

  floatx4 acc[2][4];
#pragma unroll
  for (int m = 0; m < 2; ++m)
#pragma unroll
    for (int n = 0; n < 4; ++n) acc[m][n] = (floatx4){0.f, 0.f, 0.f, 0.f};

  const int abase = lr * ASTB + quad * 8;

  for (int s = 0; s < NSLAB; ++s) {
    __syncthreads();
#pragma unroll
    for (int i = 0; i < (NACH + 255) / 256; ++i) {
      const int ee = tid + i * 256;
      if (ee < NACH) {
        const int cout = ee / 18;
        const int rem = ee - cout * 18;
        const int tap = rem >> 1;
        const int part = rem & 1;
        const uint4 v = *(const uint4*)(wtp + ((size_t)(cob + cout) * 9 + tap) * CIN + s * 32 + part * 16);
        *(uint4*)(As + cout * ASTB + tap * 32 + part * 16) = v;
      }
    }
#pragma unroll
    for (int i = 0; i < (NBCH + 255) / 256; ++i) {
      const int ee = tid + i * 256;
      if (ee < NBCH) {
        const int part = ee & 1;
        const int run = ee >> 1;
        const int row = run / 66;
        const int px = run - row * 66;
        uint4 v = {0, 0, 0, 0};
        const int gx = x0 + px;
        if (gx < Wp)
          v = *(const uint4*)(inI + (size_t)s * 4 * IPL +
                              ((size_t)(y0 + row) * Wp + gx) * 32 + part * 16);
        *(uint4*)(Bs + run * BSTB + part * 16) = v;
      }
    }
    __syncthreads();

#pragma unroll
    for (int dy = 0; dy < 3; ++dy)
#pragma unroll
      for (int dx = 0; dx < 3; ++dx) {
        const int tap = dy * 3 + dx;
        const long af0 = *(const long*)(As + abase + tap * 32);
        const long af1 = *(const long*)(As + abase + 16 * ASTB + tap * 32);
        long bfr[4];
#pragma unroll
        for (int n = 0; n < 4; ++n)
          bfr[n] = *(const long*)(Bs + ((wave + dy) * 66 + n * 16 + lr + dx) * BSTB + quad * 8);
#pragma unroll
        for (int n = 0; n < 4; ++n) {
          acc[0][n] = __builtin_amdgcn_mfma_f32_16x16x32_fp8_fp8(af0, bfr[n], acc[0][n], 0, 0, 0);
          acc[1][n] = __builtin_amdgcn_mfma_f32_16x16x32_fp8_fp8(af1, bfr[n], acc[1][n], 0, 0, 0);
        }
      }
  }

#pragma unroll
  for (int m = 0; m < 2; ++m) {
    const int cb = cob + m * 16 + quad * 4;
#pragma unroll
    for (int n = 0; n < 4; ++n) {
      const int px = x0 + n * 16 + lr;
      if (px < W) {
        const float v0 = fmaxf(acc[m][n].x * 0.125f + bias[cb + 0], 0.f);
        const float v1 = fmaxf(acc[m][n].y * 0.125f + bias[cb + 1], 0.f);
        const float v2 = fmaxf(acc[m][n].z * 0.125f + bias[cb + 2], 0.f);
        const float v3 = fmaxf(acc[m][n].w * 0.125f + bias[cb + 3], 0.f);
        *(unsigned int*)(outI + ((size_t)(y0 + wave + 1) * Wp + px + 1) * 32 +
                         m * 16 + quad * 4) = pk_fp8x4(v0, v1, v2, v3);
      }
    }
  }
}

// batched 2x2 maxpool, channel-block-major fp8 (non-negative e4m3: byte max exact)
__global__ __launch_bounds__(256) void pool_nhwc(const unsigned char* __restrict__ in,
                                                 unsigned char* __restrict__ out,
                                                 int Ho, int Wo, int C) {
  const int per = Ho * Wo * (C / 8);
  const int idx = blockIdx.x * 256 + threadIdx.x;
  if (idx >= 4 * per) return;
  const int img = idx / per;
  const int k = idx - img * per;
  const int c8 = k % (C / 8);
  const int p = k / (C / 8);
  const int x = p % Wo, y = p / Wo;
  const int zb = c8 >> 2;
  const int cw = (c8 & 3) * 8;
  const int Wi = 2 * Wo + 2;
  const unsigned char* ib = in + ((size_t)(zb * 4 + img) * (2 * Ho + 2) * Wi +
                                  (size_t)(2 * y + 1) * Wi + (2 * x + 1)) * 32 + cw;
  const uchar8v a = *(const uchar8v*)(ib);
  const uchar8v b = *(const uchar8v*)(ib + 32);
  const uchar8v d = *(const uchar8v*)(ib + (size_t)Wi * 32);
  const uchar8v e = *(const uchar8v*)(ib + (size_t)Wi * 32 + 32);
  const uchar8v r = __builtin_elementwise_max(__builtin_elementwise_max(a, b),
                                              __builtin_elementwise_max(d, e));
  *(uchar8v*)(out + ((size_t)(zb * 4 + img) * (Ho + 2) * (Wo + 2) +
                     (size_t)(y + 1) * (Wo + 2) + (x + 1)) * 32 + cw) = r;
}

// perceptual: F planes [8 zb][4 img][58][58][32], pairs (img 0,2) and (1,3)
#define FP8D(av, bv, J) { const float dd = __builtin_amdgcn_cvt_f32_fp8((av), (J)) - \
                                           __builtin_amdgcn_cvt_f32_fp8((bv), (J)); \
                          v = fmaf(dd, dd, v); }
__global__ __launch_bounds__(256) void perc_k(const unsigned char* __restrict__ f,
                                              float* __restrict__ acc) {
  const int PER = 56 * 56 * 256 / 8;
  const size_t PL = (size_t)58 * 58 * 32;
  float v = 0.f;
  for (int ch = blockIdx.x * 256 + threadIdx.x; ch < 2 * PER; ch += 256 * 256) {
    const int q = ch / PER;
    const int r = ch - q * PER;
    const int e = r * 8;
    const int c = e & 255;
    const int p = e >> 8;
    const int x = p % 56, y = p / 56;
    const int zb = c >> 5;
    const int cw = c & 31;
    const size_t o = (size_t)(zb * 4 + q) * PL + ((size_t)(y + 1) * 58 + (x + 1)) * 32 + cw;
    const uint2 a = *(const uint2*)(f + o);
    const uint2 b = *(const uint2*)(f + o + 2 * PL);
    FP8D(a.x, b.x, 0) FP8D(a.x, b.x, 1) FP8D(a.x, b.x, 2) FP8D(a.x, b.x, 3)
    FP8D(a.y, b.y, 0) FP8D(a.y, b.y, 1) FP8D(a.y, b.y, 2) FP8D(a.y, b.y, 3)
  }
  const float t = blockSum256(v);
  if (threadIdx.x == 0) atomicAdd(acc + SLOT(ACC_PERC), t);
}

// ---------------- final combine ----------------
__global__ void final_k(const float* __restrict__ acc, float* __restrict__ out) {
  if (threadIdx.x != 0 || blockIdx.x != 0) return;
  const float NPIX = 2.f * 3.f * 224.f * 224.f;
  const float l1 = acc[SLOT(ACC_L1)] / NPIX;
  const float mse = acc[SLOT(ACC_MSE)] / NPIX;
  const float psnr = 40.f + 10.f * log10f(mse);
  const float cm = 1.f / (3.f * 224.f * 224.f);
  const float color = 0.5f * (fabsf(acc[SLOT(ACC_ST0)] - acc[SLOT(ACC_SP0)]) +
                              fabsf(acc[SLOT(ACC_ST1)] - acc[SLOT(ACC_SP1)])) * cm;
  const float ill = acc[SLOT(ACC_HV)] / 669.f + acc[SLOT(ACC_WV)] / 448.f;
  const float expl = acc[SLOT(ACC_EXP)] / 392.f;
  const float spat = acc[SLOT(ACC_SPAT)] / 6272.f;
  const float perc = acc[SLOT(ACC_PERC)] / 1605632.f;
  const float wms[5] = {0.0448f, 0.2856f, 0.3001f, 0.2363f, 0.1333f};
  const int ns[5] = {214, 102, 46, 18, 4};
  float msum = 0.f;
  for (int img = 0; img < 6; ++img) {
    float prod = 1.f;
    for (int s = 0; s < 5; ++s) {
      const float denom = (float)(ns[s] * ns[s]);
      float v = (s == 4) ? acc[SSIM_SLOT(s, 0, img)] / denom
                         : acc[SSIM_SLOT(s, 1, img)] / denom;
      v = fmaxf(v, 0.f);
      prod *= powf(v, wms[s]);
    }
    msum += prod;
  }
  const float msssim = msum / 6.f;
  out[0] = l1 + 0.06f * perc + 0.0083f * psnr + 0.25f * color +
           0.5f * (1.f - msssim) + 0.1f * expl + 0.1f * ill + 0.1f * spat;
}

extern "C" void kernel_launch(void* const* d_in, const int* in_sizes, int n_in,
                              void* d_out, int out_size, void* d_ws, size_t ws_size,
                              hipStream_t stream) {
  const float* yt = (const float*)d_in[0];
  const float* yp = (const float*)d_in[1];
  const float* W7[7]; const float* B7[7];
  for (int i = 0; i < 7; ++i) {
    W7[i] = (const float*)d_in[2 + 2 * i];
    B7[i] = (const float*)d_in[3 + 2 * i];
  }

  char* ws = (char*)d_ws;
  float* acc = (float*)ws;
  size_t off = 16384;
  auto align256 = [&]() { off = (off + 255) & ~(size_t)255; };
  align256(); unsigned char* C1  = (unsigned char*)(ws + off); off += (size_t)4 * 226 * 226 * 64;
  align256(); unsigned char* T0  = (unsigned char*)(ws + off); off += (size_t)4 * 226 * 226 * 64;
  align256(); unsigned char* Pl1 = (unsigned char*)(ws + off); off += (size_t)4 * 114 * 114 * 64;
  align256(); unsigned char* C3  = (unsigned char*)(ws + off); off += (size_t)4 * 114 * 114 * 128;
  align256(); unsigned char* Pl2 = (unsigned char*)(ws + off); off += (size_t)4 * 58 * 58 * 128;
  align256(); unsigned char* C5  = (unsigned char*)(ws + off); off += (size_t)4 * 58 * 58 * 256;
  align256(); unsigned char* C6  = (unsigned char*)(ws + off); off += (size_t)4 * 58 * 58 * 256;
  align256(); unsigned char* F   = (unsigned char*)(ws + off); off += (size_t)4 * 58 * 58 * 256;
  align256(); unsigned char* WT  = (unsigned char*)(ws + off); off += (size_t)1732608;
  align256(); float* pyrX = (float*)(ws + off); off += (size_t)100000 * 4;
  align256(); float* pyrY = (float*)(ws + off); off += (size_t)100000 * 4;
  if (ws_size < off) return;

  GW gw;
  {
    double vv[11]; double s = 0.0;
    for (int i = 0; i < 11; ++i) { const double c = i - 5.0; vv[i] = exp(-(c * c) / 4.5); s += vv[i]; }
    for (int i = 0; i < 11; ++i) gw.g[i] = (float)(vv[i] / s);
  }

  hipMemsetAsync(acc, 0, 16384, stream);

  // mega args: prep (weights + border zeroing) + basic + pyramid + poolspat + conv1
  const int co[7] = {64, 64, 128, 128, 256, 256, 256};
  const int ci[7] = {3, 64, 64, 128, 128, 256, 256};
  MegaArgs ma;
  size_t wtOff[7];
  {
    int e = 0;
    for (int i = 1; i < 7; ++i) {
      ma.pa.w[i - 1] = W7[i]; ma.pa.co[i - 1] = co[i]; ma.pa.ci[i - 1] = ci[i];
      ma.pa.wcum[i - 1] = e; wtOff[i] = (size_t)e; e += co[i] * 9 * ci[i];
    }
    ma.pa.wcum[6] = e;
    unsigned char* bufs[6] = {C1, Pl1, C3, Pl2, C5, C6};
    const int hh[6] = {224, 112, 112, 56, 56, 56};
    const int cc[6] = {64, 64, 128, 128, 256, 256};
    int z = 0;
    for (int i = 0; i < 6; ++i) {
      ma.pa.zp[i] = bufs[i]; ma.pa.zH[i] = hh[i]; ma.pa.zC[i] = 32;
      ma.pa.zcum[i] = z;
      z += (4 * cc[i] / 32) * (2 * (hh[i] + 2) * 32 + 2 * hh[i] * 32);
    }
    ma.pa.zcum[6] = z;
    ma.nPrep = (ma.pa.wcum[6] + z + 255) / 256;
  }
  ma.wdst = WT;
  ma.w0 = W7[0]; ma.b0 = B7[0];
  ma.c1 = C1;
  ma.pyrX = pyrX; ma.pyrY = pyrY;
  ma.acc = acc;
  ma.nBasic = 294;
  ma.nPyr = 196 * 6 * 2;
  ma.nPS = 32;
  const int nConv1 = 28 * 28 * 8;
  const int megaBlocks = ma.nPrep + ma.nBasic + ma.nPyr + ma.nPS + nConv1;

  mega_k<<<megaBlocks, 256, 0, stream>>>(ma, yt, yp);
  ssim_all_k<<<dim3(259, 6), 256, 0, stream>>>(yt, yp, pyrX, pyrY, acc, gw);

  // VGG19[:16] conv chain in fp8, all 4 images per dispatch.
  conv_mfma<64> <<<dim3(4, 4 * 56, 2), 256, 0, stream>>>(C1,  WT + wtOff[1], B7[1], T0, 224, 56);
  pool_nhwc<<<(4 * 112 * 112 * 8 + 255) / 256, 256, 0, stream>>>(T0, Pl1, 112, 112, 64);
  conv_mfma<64> <<<dim3(2, 4 * 28, 4), 256, 0, stream>>>(Pl1, WT + wtOff[2], B7[2], C3, 112, 28);
  conv_mfma<128><<<dim3(2, 4 * 28, 4), 256, 0, stream>>>(C3,  WT + wtOff[3], B7[3], T0, 112, 28);
  pool_nhwc<<<(4 * 56 * 56 * 16 + 255) / 256, 256, 0, stream>>>(T0, Pl2, 56, 56, 128);
  conv_mfma<128><<<dim3(1, 4 * 14, 8), 256, 0, stream>>>(Pl2, WT + wtOff[4], B7[4], C5, 56, 14);
  conv_mfma<256><<<dim3(1, 4 * 14, 8), 256, 0, stream>>>(C5,  WT + wtOff[5], B7[5], C6, 56, 14);
  conv_mfma<256><<<dim3(1, 4 * 14, 8), 256, 0, stream>>>(C6,  WT + wtOff[6], B7[6], F,  56, 14);
  perc_k<<<256, 256, 0, stream>>>(F, acc);

  final_k<<<1, 64, 0, stream>>>(acc, (float*)d_out);
}